// Round 10
// baseline (191.319 us; speedup 1.0000x reference)
//
#include <hip/hip_runtime.h>
#include <hip/hip_bf16.h>
#include <math.h>

#define NBATCH 8
#define NBOX   20000
#define NCLS   80
#define NREL   51
#define MAXDET 300
#define NTOT   (NCLS * MAXDET)      // 24000
#define CAP    512
#define SPECCAP 2560
#define NHB    3328
#define HB0    (0x3F666666u >> 9)   // bucket base = bits(0.9f) >> 9
#define TARGETK 480u
#define SCORE_THR 0.05f
#define SPEC_THRF 0.9f

typedef unsigned long long u64;
typedef unsigned int u32;

// IoU > 0.5, explicit IEEE div (k_slow only).
__device__ __forceinline__ bool iou_sup(float ax1, float ay1, float ax2, float ay2, float aarea,
                                        float bx1, float by1, float bx2, float by2, float barea) {
  float ix1 = fmaxf(ax1, bx1);
  float iy1 = fmaxf(ay1, by1);
  float ix2 = fminf(ax2, bx2);
  float iy2 = fminf(ay2, by2);
  float dw = fmaxf(__fsub_rn(ix2, ix1), 0.0f);
  float dh = fmaxf(__fsub_rn(iy2, iy1), 0.0f);
  float inter = __fmul_rn(dw, dh);
  float uni = __fsub_rn(__fadd_rn(aarea, barea), inter);
  if (!(uni > 0.0f)) return false;
  return __fdiv_rn(inter, uni) > 0.5f;
}

__device__ __forceinline__ bool iou_gt_half(float ax1, float ay1, float ax2, float ay2,
                                            float bx1, float by1, float bx2, float by2) {
  float aa = __fmul_rn(__fsub_rn(ax2, ax1), __fsub_rn(ay2, ay1));
  float ab = __fmul_rn(__fsub_rn(bx2, bx1), __fsub_rn(by2, by1));
  return iou_sup(ax1, ay1, ax2, ay2, aa, bx1, by1, bx2, by2, ab);
}

// Bit-exact div-free IoU>0.5 in PURE f32:
//   rn32(inter/uni) > 0.5  ⟺  inter/uni > 0.5(1+2^-24)   (tie->even = 0.5)
//   f32 test inter > 0.5*uni differs only if a float inter lies in
//   (0.5uni, 0.5uni(1+2^-24)] — impossible: succ(a) = a(1+2^-23/m), m<2.
// Note: operand-symmetric (fadd/fmax commutative bitwise for non-NaN).
__device__ __forceinline__ bool iou_sup_fast(float ax1, float ay1, float ax2, float ay2,
                                             float aarea, float bx1, float by1, float bx2,
                                             float by2, float barea) {
  float ix1 = fmaxf(ax1, bx1);
  float iy1 = fmaxf(ay1, by1);
  float ix2 = fminf(ax2, bx2);
  float iy2 = fminf(ay2, by2);
  float dw = fmaxf(__fsub_rn(ix2, ix1), 0.0f);
  float dh = fmaxf(__fsub_rn(iy2, iy1), 0.0f);
  float inter = __fmul_rn(dw, dh);
  float uni = __fsub_rn(__fadd_rn(aarea, barea), inter);
  return (uni > 0.0f) && (inter > __fmul_rn(0.5f, uni));
}

#define CEXR(x, y, asc) { bool sw_ = (asc) ? ((x) > (y)) : ((x) < (y)); \
                          if (sw_) { u64 t_ = (x); (x) = (y); (y) = t_; } }

// Bitonic sort ascending over SZ u64 keys in LDS; 256-thread block.
__device__ __forceinline__ void bitonic_sort(u64* keys, int SZ, int tid) {
  for (int k = 2; k <= SZ; k <<= 1) {
    for (int j = k >> 1; j >= 4; j >>= 1) {
      for (int v = tid; v < (SZ >> 1); v += 256) {
        int i = ((v & ~(j - 1)) << 1) | (v & (j - 1));
        int p = i | j;
        bool asc = ((i & k) == 0);
        u64 a = keys[i], b = keys[p];
        bool sw = asc ? (a > b) : (a < b);
        if (sw) { keys[i] = b; keys[p] = a; }
      }
      __syncthreads();
    }
    if (tid < (SZ >> 2)) {
      ulonglong2* k2 = (ulonglong2*)keys;
      ulonglong2 lo = k2[tid * 2], hi = k2[tid * 2 + 1];
      u64 a = lo.x, b = lo.y, c = hi.x, d = hi.y;
      int i0 = tid << 2;
      if (k == 2) {
        CEXR(a, b, true); CEXR(c, d, false);
      } else {
        bool asc = ((i0 & k) == 0);
        CEXR(a, c, asc); CEXR(b, d, asc);  // j = 2
        CEXR(a, b, asc); CEXR(c, d, asc);  // j = 1
      }
      lo.x = a; lo.y = b; hi.x = c; hi.y = d;
      k2[tid * 2] = lo; k2[tid * 2 + 1] = hi;
    }
    __syncthreads();
  }
}

// Barrier-light suffix select over NB buckets (LDS or global hist):
// minimal suffix >= min(total, cap). sout: [0]=bucket [1]=sel [2]=above [3]=total.
template <int NB>
__device__ __forceinline__ void suffix_fast(const u32* hist, u32 cap, u32* wsum4, u32* sout) {
  const int tid = threadIdx.x, lane = tid & 63, w = tid >> 6;
  const int G = NB / 256;
  u32 v = 0;
  const int hb = tid * G;
#pragma unroll
  for (int t = 0; t < G; ++t) v += hist[hb + t];
  u32 s = v;
#pragma unroll
  for (int off = 1; off < 64; off <<= 1) {
    u32 t2 = __shfl_down(s, off);
    if (lane + off < 64) s += t2;
  }
  if (lane == 0) wsum4[w] = s;
  __syncthreads();
  u32 total = wsum4[0] + wsum4[1] + wsum4[2] + wsum4[3];
  u32 after = 0;
#pragma unroll
  for (int ww = 1; ww < 4; ++ww) if (ww > w) after += wsum4[ww];
  u32 inc = s + after;
  u32 exc = inc - v;
  if (tid == 0) {
    sout[3] = total;
    if (total == 0u) { sout[0] = 0u; sout[1] = 0u; sout[2] = 0u; }
  }
  u32 target = total < cap ? total : cap;
  if (total != 0u && inc >= target && exc < target) {  // exactly one thread
    u32 acc = exc;
    for (int u = hb + G - 1; u >= hb; --u) {
      acc += hist[u];
      if (acc >= target) { sout[0] = (u32)u; sout[1] = acc; sout[2] = acc - hist[u]; break; }
    }
  }
  __syncthreads();
}

// Transpose cls (B,N,C) -> colS (B,C,N). Block x==0 zeroes per-batch topk scratch.
__global__ __launch_bounds__(256) void k_tr(const float* __restrict__ cls,
                                            float* __restrict__ colS,
                                            u32* __restrict__ ghist,
                                            u32* __restrict__ gtail) {
  __shared__ float tile[NCLS * 65];
  const int tid = threadIdx.x;
  const int b = blockIdx.y;
  const int n0 = blockIdx.x * 64;
  if (blockIdx.x == 0) {
    for (int i = tid; i < NHB; i += 256) ghist[b * NHB + i] = 0u;
    if (tid == 0) gtail[b] = 0u;
  }
  const int rows = (NBOX - n0) < 64 ? (NBOX - n0) : 64;
  const float4* src4 = (const float4*)(cls + ((size_t)b * NBOX + n0) * NCLS);
  const int nq = rows * (NCLS / 4);
  for (int i = tid; i < nq; i += 256) {
    int rr = i / (NCLS / 4);
    int c4 = i - rr * (NCLS / 4);
    float4 v = src4[i];
    tile[(c4 * 4 + 0) * 65 + rr] = v.x;
    tile[(c4 * 4 + 1) * 65 + rr] = v.y;
    tile[(c4 * 4 + 2) * 65 + rr] = v.z;
    tile[(c4 * 4 + 3) * 65 + rr] = v.w;
  }
  __syncthreads();
  float4* dst4 = (float4*)colS;
  for (int i = tid; i < NCLS * 16; i += 256) {
    int c = i >> 4, nl = i & 15;
    if (nl * 4 < rows) {
      float4 v;
      v.x = tile[c * 65 + nl * 4 + 0];
      v.y = tile[c * 65 + nl * 4 + 1];
      v.z = tile[c * 65 + nl * 4 + 2];
      v.w = tile[c * 65 + nl * 4 + 3];
      dst4[(((size_t)b * NCLS + c) * NBOX + n0) / 4 + nl] = v;
    }
  }
}

// Zero scratch when transpose path is unavailable.
__global__ __launch_bounds__(256) void k_zero(u32* __restrict__ ghist,
                                              u32* __restrict__ gtail) {
  const int b = blockIdx.x;
  const int tid = threadIdx.x;
  for (int i = tid; i < NHB; i += 256) ghist[b * NHB + i] = 0u;
  if (tid == 0) gtail[b] = 0u;
}

template <int STRIDE>
__device__ __forceinline__ float4 load4s(const float* col, int q) {
  if (STRIDE == 1) return ((const float4*)col)[q];
  float4 v;
  v.x = col[(size_t)(q * 4 + 0) * STRIDE];
  v.y = col[(size_t)(q * 4 + 1) * STRIDE];
  v.z = col[(size_t)(q * 4 + 2) * STRIDE];
  v.w = col[(size_t)(q * 4 + 3) * STRIDE];
  return v;
}

// Phase A: single scan + speculative (>0.9) side buffer + flat 512-ULP histogram ->
// exact top-~TARGETK selection -> bitonic sort -> sorted keys to global.
template <int STRIDE>
__global__ __launch_bounds__(256) void k_sel(const float* __restrict__ scores,
                                             u64* __restrict__ keysBase, size_t kstride,
                                             int* __restrict__ selCnt,
                                             int* __restrict__ totCnt,
                                             int* __restrict__ flags) {
  __shared__ __align__(16) char smem[SPECCAP * 8 + NHB * 4 + CAP * 8];
  u64* side = (u64*)smem;
  u32* hist = (u32*)(smem + SPECCAP * 8);
  u64* keys = (u64*)(smem + SPECCAP * 8 + NHB * 4);
  __shared__ u32 wsum[4], selB[4], twave[4];
  __shared__ u32 s_scnt, s_cnt;

  const int tid = threadIdx.x;
  const int lane = tid & 63;
  const int w = tid >> 6;
  const u64 lmask = (1ull << lane) - 1ull;
  const int bc = blockIdx.x;
  const int b = bc / NCLS, c = bc % NCLS;
  const float* col = (STRIDE == 1) ? (scores + (size_t)bc * NBOX)
                                   : (scores + (size_t)b * NBOX * NCLS + c);

  for (int i = tid; i < NHB; i += 256) hist[i] = 0u;
  if (tid == 0) { s_scnt = 0u; s_cnt = 0u; }
  __syncthreads();

  u32 tailc = 0;
  for (int base = 0; base < NBOX / 4; base += 2048) {
    float4 v[8];
#pragma unroll
    for (int p = 0; p < 8; ++p) {
      int q = base + tid + (p << 8);
      if (q < NBOX / 4) v[p] = load4s<STRIDE>(col, q);
    }
#pragma unroll
    for (int p = 0; p < 8; ++p) {
      int q = base + tid + (p << 8);
      if (q < NBOX / 4) {
        float vv[4] = {v[p].x, v[p].y, v[p].z, v[p].w};
#pragma unroll
        for (int e = 0; e < 4; ++e) {
          float s = vv[e];
          bool spec = s > SPEC_THRF;
          if (s > SCORE_THR && !spec) ++tailc;
          u64 mb = __ballot(spec);
          if (mb) {
            u32 bs;
            if (lane == 0) bs = atomicAdd(&s_scnt, (u32)__popcll(mb));
            bs = __shfl(bs, 0);
            if (spec) {
              u32 bits = __float_as_uint(s);
              u32 pos = bs + (u32)__popcll(mb & lmask);
              if (pos < SPECCAP) side[pos] = ((u64)bits << 32) | (~(u32)(q * 4 + e));
              u32 h = (bits >> 9) - HB0;
              if (h > NHB - 1) h = NHB - 1;
              atomicAdd(&hist[h], 1u);
            }
          }
        }
      }
    }
  }
  u32 tr = tailc;
#pragma unroll
  for (int off = 1; off < 64; off <<= 1) tr += __shfl_down(tr, off);
  if (lane == 0) twave[w] = tr;
  __syncthreads();

  const u32 specCount = s_scnt;
  const u32 tailSum = twave[0] + twave[1] + twave[2] + twave[3];
  const u32 totalAll = specCount + tailSum;

  if (totalAll == 0u) {
    if (tid == 0) { selCnt[bc] = 0; totCnt[bc] = 0; flags[bc] = 0; }
    return;
  }
  const u32 target = totalAll < TARGETK ? totalAll : TARGETK;
  if (specCount < target || specCount > SPECCAP) {
    if (tid == 0) { selCnt[bc] = 0; totCnt[bc] = (int)totalAll; flags[bc] = 1; }
    return;
  }

  suffix_fast<NHB>(hist, target, wsum, selB);
  const u32 F0 = selB[0];
  const u32 selCount = selB[1];
  if (selCount > CAP) {
    if (tid == 0) { selCnt[bc] = 0; totCnt[bc] = (int)totalAll; flags[bc] = 1; }
    return;
  }

  const int iters = (int)((specCount + 255u) >> 8);
  for (int it2 = 0; it2 < iters; ++it2) {
    u32 idx = (u32)it2 * 256u + (u32)tid;
    bool act = idx < specCount;
    u64 key = act ? side[idx] : 0ull;
    u32 bits = (u32)(key >> 32);
    u32 h = (bits >> 9) - HB0;
    if (h > NHB - 1) h = NHB - 1;
    bool sel = act && (h >= F0);
    u64 ms = __ballot(sel);
    if (ms) {
      u32 bs;
      if (lane == 0) bs = atomicAdd(&s_cnt, (u32)__popcll(ms));
      bs = __shfl(bs, 0);
      if (sel) keys[bs + (u32)__popcll(ms & lmask)] = key;
    }
  }
  __syncthreads();
  for (int i = (int)selCount + tid; i < CAP; i += 256) keys[i] = 0ull;
  __syncthreads();

  bitonic_sort(keys, CAP, tid);

  u64* kout = keysBase + (size_t)bc * kstride;
  for (int i = tid; i < CAP; i += 256) kout[i] = keys[i];
  if (tid == 0) { selCnt[bc] = (int)selCount; totCnt[bc] = (int)totalAll; flags[bc] = 0; }
}

// Phase B: suppression-matrix NMS walk.
//  1) gather candidate boxes (descending score order; candidate c <-> keys[CAP-1-c])
//  2) build column bitmasks colM[c][w] = {i in word w, i<c : IoU(i,c)>0.5} —
//     fully parallel, no barriers/atomics; wave-broadcast LDS reads
//  3) wave-0-only greedy walk over 64-chunks using the matrix (K mask in registers)
// On success, also histograms kept scores into the per-batch global hist.
__global__ __launch_bounds__(512) void k_walk(const float* __restrict__ boxes,
                                              const u64* __restrict__ keysBase, size_t kstride,
                                              const int* __restrict__ selCnt,
                                              const int* __restrict__ totCnt,
                                              float* __restrict__ keptScore,
                                              int* __restrict__ keptN,
                                              int* __restrict__ keptCount,
                                              int* __restrict__ flags,
                                              u32* __restrict__ ghist,
                                              u32* __restrict__ gtail) {
  __shared__ __align__(16) char smem[47104];
  u64* keys = (u64*)smem;                   // [512]   @0
  float4* candbox = (float4*)(smem + 4096); // [512]   @4096
  float* carea = (float*)(smem + 12288);    // [512]   @12288
  u64* colM = (u64*)(smem + 14336);         // [512*8] @14336 (32 KB)
  __shared__ unsigned short keptIdx[MAXDET];
  __shared__ int s_kept;

  const int tid = threadIdx.x;
  const int lane = tid & 63;
  const int w = tid >> 6;
  const u64 lmask = (1ull << lane) - 1ull;
  const int bc = blockIdx.x;
  const int b = bc / NCLS;

  if (flags[bc] != 0) return;  // k_slow produces this problem exactly
  const u32 selCount = (u32)selCnt[bc];
  const u32 totalAll = (u32)totCnt[bc];

  const u64* kin = keysBase + (size_t)bc * kstride;
  for (int i = tid; i < CAP; i += 512) keys[i] = kin[i];
  if (tid == 0) s_kept = 0;
  __syncthreads();

  // Gather boxes in candidate order (c=0 highest score).
  for (int i = tid; i < (int)selCount; i += 512) {
    u32 n = ~((u32)keys[CAP - 1 - i]);
    float4 bb = ((const float4*)boxes)[(size_t)b * NBOX + n];
    candbox[i] = bb;
    carea[i] = __fmul_rn(__fsub_rn(bb.z, bb.x), __fsub_rn(bb.w, bb.y));
  }
  __syncthreads();

  // Matrix build: task -> (c = task&511, wd = task>>9). Wave v round k: all lanes
  // read the SAME candbox[i] per step (broadcast); waves with no work finish early.
  for (int task = tid; task < CAP * 8; task += 512) {
    int c = task & (CAP - 1);
    int wd = task >> 9;
    u64 bits = 0ull;
    if (c < (int)selCount) {
      int jmax = c - (wd << 6);
      if (jmax > 64) jmax = 64;
      if (jmax > 0) {
        float4 myb = candbox[c];
        float ma = carea[c];
        for (int jj = 0; jj < 64; ++jj) {
          if (jj < jmax) {
            int i = (wd << 6) + jj;
            float4 ib = candbox[i];
            if (iou_sup_fast(ib.x, ib.y, ib.z, ib.w, carea[i],
                             myb.x, myb.y, myb.z, myb.w, ma))
              bits |= 1ull << jj;
          }
        }
      }
    }
    colM[c * 8 + wd] = bits;
  }
  __syncthreads();

  // Walk: wave 0 only, kept-mask K in registers (lane l<8 owns word l). No barriers.
  if (w == 0) {
    u64 Kreg = 0ull;
    int kept = 0;
    const u32 ntile = (selCount + 63u) >> 6;
    for (u32 t = 0; t < ntile && kept < MAXDET; ++t) {
      const int c = (int)(t * 64u) + lane;
      const bool valid = c < (int)selCount;
      const u64* myCol = &colM[c * 8];
      u64 prior = 0ull;
      for (int wd = 0; wd < (int)t; ++wd) {
        u64 kw = __shfl(Kreg, wd);
        prior |= myCol[wd] & kw;
      }
      u64 m = myCol[t];   // in-chunk suppressors (bits i<c only, by construction)
      u64 remaining = __ballot(valid && prior == 0ull);
      u64 keptmask = 0ull;
      const int room = MAXDET - kept;
      while (remaining != 0ull && (int)__popcll(keptmask) < room) {
        int j = __ffsll((long long)remaining) - 1;
        keptmask |= 1ull << j;
        remaining &= ~(1ull << j);
        u64 supj = __ballot(((m >> j) & 1ull) != 0ull);
        remaining &= ~supj;
      }
      if ((keptmask >> lane) & 1ull)
        keptIdx[kept + (int)__popcll(keptmask & lmask)] = (unsigned short)c;
      kept += (int)__popcll(keptmask);
      if (lane == (int)t) Kreg |= keptmask;
    }
    if (lane == 0) s_kept = kept;
  }
  __syncthreads();

  const int kept = s_kept;
  const bool exhausted = (kept < MAXDET && selCount < totalAll);
  for (int rr = tid; rr < MAXDET; rr += 512) {
    float sc = -INFINITY;
    int n = 0;
    if (rr < kept) {
      u64 key = keys[CAP - 1 - (int)keptIdx[rr]];
      sc = __uint_as_float((u32)(key >> 32));
      n = (int)(~((u32)key));
    }
    keptScore[bc * MAXDET + rr] = sc;
    keptN[bc * MAXDET + rr] = n;
  }
  if (tid == 0) {
    keptCount[bc] = kept;
    flags[bc] = exhausted ? 1 : 0;
  }
  if (!exhausted) {  // contribute kept scores to the per-batch top-k histogram
    for (int rr = tid; rr < kept; rr += 512) {
      float s = __uint_as_float((u32)(keys[CAP - 1 - (int)keptIdx[rr]] >> 32));
      if (s > SPEC_THRF) {
        u32 h = (__float_as_uint(s) >> 9) - HB0;
        if (h > NHB - 1) h = NHB - 1;
        atomicAdd(&ghist[b * NHB + h], 1u);
      } else {
        atomicAdd(&gtail[b], 1u);
      }
    }
  }
}

// Exact reference-style greedy NMS for flagged problems (expected: none fire).
// Also contributes its kept scores to the per-batch histogram.
__global__ __launch_bounds__(256) void k_slow(const float* __restrict__ boxes,
                                              const float* __restrict__ cls,
                                              float* __restrict__ keptScore,
                                              int* __restrict__ keptN,
                                              int* __restrict__ keptCount,
                                              const int* __restrict__ flags,
                                              u32* __restrict__ ghist,
                                              u32* __restrict__ gtail) {
  const int bc = blockIdx.x;
  if (flags[bc] != 1) return;
  const int tid = threadIdx.x;
  const int b = bc / NCLS, c = bc % NCLS;
  const float* col = cls + (size_t)b * NBOX * NCLS + c;
  __shared__ u32 sup[(NBOX + 31) / 32];
  __shared__ u64 red[256];
  __shared__ float4 sbx;
  __shared__ int s_kept;
  for (int i = tid; i < (NBOX + 31) / 32; i += 256) sup[i] = 0u;
  if (tid == 0) s_kept = 0;
  __syncthreads();
  for (int it = 0; it < MAXDET; ++it) {
    u64 best = 0ull;
    for (int n = tid; n < NBOX; n += 256) {
      if ((sup[n >> 5] >> (n & 31)) & 1u) continue;
      float s = col[(size_t)n * NCLS];
      if (s > SCORE_THR) {
        u64 key = ((u64)__float_as_uint(s) << 32) | (~(u32)n);
        if (key > best) best = key;
      }
    }
    red[tid] = best;
    __syncthreads();
    for (int off = 128; off > 0; off >>= 1) {
      if (tid < off) { u64 o = red[tid + off]; if (o > red[tid]) red[tid] = o; }
      __syncthreads();
    }
    u64 win = red[0];
    if (win == 0ull) break;
    u32 nw = ~((u32)win);
    if (tid == 0) {
      int k = s_kept;
      keptScore[bc * MAXDET + k] = __uint_as_float((u32)(win >> 32));
      keptN[bc * MAXDET + k] = (int)nw;
      s_kept = k + 1;
      sbx = ((const float4*)boxes)[(size_t)b * NBOX + nw];
    }
    __syncthreads();
    float4 bx = sbx;
    for (int n = tid; n < NBOX; n += 256) {
      float4 cb = ((const float4*)boxes)[(size_t)b * NBOX + n];
      if (iou_gt_half(bx.x, bx.y, bx.z, bx.w, cb.x, cb.y, cb.z, cb.w))
        atomicOr(&sup[n >> 5], 1u << (n & 31));
    }
    if (tid == 0) atomicOr(&sup[nw >> 5], 1u << (nw & 31));
    __syncthreads();
  }
  __syncthreads();
  const int kept = s_kept;
  for (int r = kept + tid; r < MAXDET; r += 256) {
    keptScore[bc * MAXDET + r] = -INFINITY;
    keptN[bc * MAXDET + r] = 0;
  }
  for (int rr = tid; rr < kept; rr += 256) {
    float s = keptScore[bc * MAXDET + rr];
    if (s > SPEC_THRF) {
      u32 h = (__float_as_uint(s) >> 9) - HB0;
      if (h > NHB - 1) h = NHB - 1;
      atomicAdd(&ghist[b * NHB + h], 1u);
    } else {
      atomicAdd(&gtail[b], 1u);
    }
  }
  if (tid == 0) keptCount[bc] = kept;
}

// Top-k + outputs: suffix-select from prebuilt per-batch hist -> compact scan ->
// bitonic-512 (exact lax.top_k ties) -> emit. Fallback: exact serial 80-way merge.
__global__ __launch_bounds__(256) void k_osort(const float* __restrict__ boxes,
                                               const float* __restrict__ rel,
                                               const float* __restrict__ keptScore,
                                               const int* __restrict__ keptN,
                                               const u32* __restrict__ ghist,
                                               const u32* __restrict__ gtail,
                                               float* __restrict__ out) {
  __shared__ u64 keys[1024];
  __shared__ u32 wsum[4], selB[4];
  __shared__ u32 s_cnt;
  const int tid = threadIdx.x;
  const int lane = tid & 63;
  const u64 lmask = (1ull << lane) - 1ull;
  const int b = blockIdx.x;
  const float4* ks4 = (const float4*)(keptScore + (size_t)b * NTOT);

  if (tid == 0) s_cnt = 0u;
  suffix_fast<NHB>(ghist + (size_t)b * NHB, (u32)MAXDET, wsum, selB);
  const u32 specTotal = selB[3];
  const u32 totalAll = specTotal + gtail[b];
  const u32 target = totalAll < (u32)MAXDET ? totalAll : (u32)MAXDET;
  const u32 F0 = selB[0];
  const u32 selSpec = selB[1];
  const bool fast = (totalAll != 0u) && (specTotal >= target) && (selSpec <= (u32)CAP);
  int SZ = CAP;

  if (totalAll != 0u) {
    if (fast) {
      for (int base = 0; base < NTOT / 4; base += 2048) {
        float4 v[8];
#pragma unroll
        for (int p = 0; p < 8; ++p) {
          int q = base + tid + (p << 8);
          if (q < NTOT / 4) v[p] = ks4[q];
        }
#pragma unroll
        for (int p = 0; p < 8; ++p) {
          int q = base + tid + (p << 8);
          if (q < NTOT / 4) {
            float vv[4] = {v[p].x, v[p].y, v[p].z, v[p].w};
#pragma unroll
            for (int e = 0; e < 4; ++e) {
              float s = vv[e];
              bool sel = false;
              u32 bits = 0;
              if (s > SPEC_THRF) {
                bits = __float_as_uint(s);
                u32 h = (bits >> 9) - HB0;
                if (h > NHB - 1) h = NHB - 1;
                sel = (h >= F0);
              }
              u64 ms = __ballot(sel);
              if (ms) {
                u32 bs;
                if (lane == 0) bs = atomicAdd(&s_cnt, (u32)__popcll(ms));
                bs = __shfl(bs, 0);
                if (sel)
                  keys[bs + (u32)__popcll(ms & lmask)] =
                      ((u64)bits << 32) | (~(u32)(q * 4 + e));
              }
            }
          }
        }
      }
      __syncthreads();
      for (int i = (int)selSpec + tid; i < CAP; i += 256) keys[i] = 0ull;
      __syncthreads();
      bitonic_sort(keys, CAP, tid);
      SZ = CAP;
    } else {
      // Exact fallback: serial 80-way merge of the sorted per-class lists.
      if (tid < 64) {
        const int c0 = lane, c1 = 64 + lane;
        const bool has1 = (c1 < NCLS);
        const float* ls0 = keptScore + ((size_t)b * NCLS + c0) * MAXDET;
        const float* ls1 = keptScore + ((size_t)b * NCLS + (has1 ? c1 : c0)) * MAXDET;
        int h0 = 0, h1 = 0;
        float v0 = ls0[0], w0v = ls0[1];
        float v1 = has1 ? ls1[0] : -INFINITY;
        float w1v = has1 ? ls1[1] : -INFINITY;
        for (int r = 0; r < (int)target; ++r) {
          float bs; int bcl;
          if (has1 && v1 > v0) { bs = v1; bcl = c1; } else { bs = v0; bcl = c0; }
#pragma unroll
          for (int off = 32; off > 0; off >>= 1) {
            float os = __shfl_xor(bs, off);
            int oc = __shfl_xor(bcl, off);
            if (os > bs || (os == bs && oc < bcl)) { bs = os; bcl = oc; }
          }
          if (bcl == c0) {
            keys[1023 - r] = ((u64)__float_as_uint(bs) << 32) | (~(u32)(c0 * MAXDET + h0));
            ++h0; v0 = w0v; w0v = (h0 + 1 < MAXDET) ? ls0[h0 + 1] : -INFINITY;
          } else if (has1 && bcl == c1) {
            keys[1023 - r] = ((u64)__float_as_uint(bs) << 32) | (~(u32)(c1 * MAXDET + h1));
            ++h1; v1 = w1v; w1v = (h1 + 1 < MAXDET) ? ls1[h1 + 1] : -INFINITY;
          }
        }
      }
      __syncthreads();
      SZ = 1024;
    }
  }

  for (int r = tid; r < MAXDET; r += 256) {
    const bool valid = (u32)r < target;
    float s = -1.0f, pm = -1.0f, pl = -1.0f, cl = -1.0f;
    float4 ob; ob.x = ob.y = ob.z = ob.w = -1.0f;
    if (valid) {
      u64 key = keys[SZ - 1 - r];
      u32 fp = ~((u32)key);
      int c = (int)(fp / MAXDET);
      int slot = (int)(fp - (u32)c * MAXDET);
      int n = keptN[((size_t)b * NCLS + c) * MAXDET + slot];
      s = __uint_as_float((u32)(key >> 32));
      cl = (float)c;
      size_t nb = (size_t)b * NBOX + (u32)n;
      ob = ((const float4*)boxes)[nb];
      const float* rp = rel + nb * NREL;
      float vr[NREL];
#pragma unroll
      for (int p = 0; p < NREL; ++p) vr[p] = rp[p];  // all loads in flight
      float best = vr[0]; int bi = 0;
#pragma unroll
      for (int p = 1; p < NREL; ++p) { if (vr[p] > best) { best = vr[p]; bi = p; } }
      pm = best; pl = (float)bi;
    }
    ((float4*)out)[(size_t)b * MAXDET + r] = ob;
    const int sbase = NBATCH * MAXDET * 4;
    out[sbase + b * MAXDET + r] = s;
    out[sbase + NBATCH * MAXDET + b * MAXDET + r] = cl;
    out[sbase + 2 * NBATCH * MAXDET + b * MAXDET + r] = pm;
    out[sbase + 3 * NBATCH * MAXDET + b * MAXDET + r] = pl;
  }
}

extern "C" void kernel_launch(void* const* d_in, const int* in_sizes, int n_in,
                              void* d_out, int out_size, void* d_ws, size_t ws_size,
                              hipStream_t stream) {
  (void)in_sizes; (void)n_in; (void)out_size;
  const float* boxes = (const float*)d_in[0];
  const float* cls   = (const float*)d_in[1];
  const float* rel   = (const float*)d_in[2];
  float* out = (float*)d_out;
  char* ws = (char*)d_ws;

  const size_t trBytes = (size_t)NBATCH * NCLS * NBOX * 4;  // 51.2 MB
  const size_t NP = NBATCH * NCLS;                          // 640 problems

  float* colS = (float*)ws;
  size_t off = 0;
  const size_t oKeptScore = off; off += NP * MAXDET * 4;
  const size_t oKeptN     = off; off += NP * MAXDET * 4;
  const size_t oKeptCount = off; off += NP * 4;
  const size_t oFlags     = off; off += NP * 4;
  const size_t oSelCnt    = off; off += NP * 4;
  const size_t oTotCnt    = off; off += NP * 4;
  const size_t oKeysSep   = off; off += NP * CAP * 8;
  const size_t oGhist     = off; off += (size_t)NBATCH * NHB * 4;
  const size_t oGtail     = off; off += NBATCH * 4;
  const size_t kbaseBytes = off;

  const bool useTr = ws_size >= trBytes + kbaseBytes;
  char* kbase = useTr ? (ws + trBytes) : ws;

  float* keptScore = (float*)(kbase + oKeptScore);
  int* keptN = (int*)(kbase + oKeptN);
  int* keptCount = (int*)(kbase + oKeptCount);
  int* flags = (int*)(kbase + oFlags);
  int* selCnt = (int*)(kbase + oSelCnt);
  int* totCnt = (int*)(kbase + oTotCnt);
  u64* keysSep = (u64*)(kbase + oKeysSep);
  u32* ghist = (u32*)(kbase + oGhist);
  u32* gtail = (u32*)(kbase + oGtail);

  u64* keysBase = useTr ? (u64*)colS : keysSep;
  const size_t kstride = useTr ? (size_t)(NBOX / 2) : (size_t)CAP;

  if (useTr) {
    k_tr<<<dim3((NBOX + 63) / 64, NBATCH), 256, 0, stream>>>(cls, colS, ghist, gtail);
    k_sel<1><<<NP, 256, 0, stream>>>(colS, keysBase, kstride, selCnt, totCnt, flags);
  } else {
    k_zero<<<NBATCH, 256, 0, stream>>>(ghist, gtail);
    k_sel<NCLS><<<NP, 256, 0, stream>>>(cls, keysBase, kstride, selCnt, totCnt, flags);
  }
  k_walk<<<NP, 512, 0, stream>>>(boxes, keysBase, kstride, selCnt, totCnt,
                                 keptScore, keptN, keptCount, flags, ghist, gtail);
  k_slow<<<NP, 256, 0, stream>>>(boxes, cls, keptScore, keptN, keptCount, flags,
                                 ghist, gtail);
  k_osort<<<NBATCH, 256, 0, stream>>>(boxes, rel, keptScore, keptN, ghist, gtail, out);
}

// Round 11
// 176.299 us; speedup vs baseline: 1.0852x; 1.0852x over previous
//
#include <hip/hip_runtime.h>
#include <hip/hip_bf16.h>
#include <math.h>

#define NBATCH 8
#define NBOX   20000
#define NCLS   80
#define NREL   51
#define MAXDET 300
#define NTOT   (NCLS * MAXDET)      // 24000
#define CAP    512
#define SPECCAP 2560
#define NHB    3328
#define HB0    (0x3F666666u >> 9)   // bucket base = bits(0.9f) >> 9
#define TARGETK 480u
#define SCORE_THR 0.05f
#define SPEC_THRF 0.9f

typedef unsigned long long u64;
typedef unsigned int u32;

// IoU > 0.5, explicit IEEE div (k_slow only).
__device__ __forceinline__ bool iou_sup(float ax1, float ay1, float ax2, float ay2, float aarea,
                                        float bx1, float by1, float bx2, float by2, float barea) {
  float ix1 = fmaxf(ax1, bx1);
  float iy1 = fmaxf(ay1, by1);
  float ix2 = fminf(ax2, bx2);
  float iy2 = fminf(ay2, by2);
  float dw = fmaxf(__fsub_rn(ix2, ix1), 0.0f);
  float dh = fmaxf(__fsub_rn(iy2, iy1), 0.0f);
  float inter = __fmul_rn(dw, dh);
  float uni = __fsub_rn(__fadd_rn(aarea, barea), inter);
  if (!(uni > 0.0f)) return false;
  return __fdiv_rn(inter, uni) > 0.5f;
}

__device__ __forceinline__ bool iou_gt_half(float ax1, float ay1, float ax2, float ay2,
                                            float bx1, float by1, float bx2, float by2) {
  float aa = __fmul_rn(__fsub_rn(ax2, ax1), __fsub_rn(ay2, ay1));
  float ab = __fmul_rn(__fsub_rn(bx2, bx1), __fsub_rn(by2, by1));
  return iou_sup(ax1, ay1, ax2, ay2, aa, bx1, by1, bx2, by2, ab);
}

// Bit-exact div-free IoU>0.5 in PURE f32:
//   rn32(inter/uni) > 0.5  ⟺  inter/uni > 0.5(1+2^-24)   (tie->even = 0.5)
//   f32 test inter > 0.5*uni differs only if a float inter lies in
//   (0.5uni, 0.5uni(1+2^-24)] — impossible: succ(a) = a(1+2^-23/m), m<2.
__device__ __forceinline__ bool iou_sup_fast(float ax1, float ay1, float ax2, float ay2,
                                             float aarea, float bx1, float by1, float bx2,
                                             float by2, float barea) {
  float ix1 = fmaxf(ax1, bx1);
  float iy1 = fmaxf(ay1, by1);
  float ix2 = fminf(ax2, bx2);
  float iy2 = fminf(ay2, by2);
  float dw = fmaxf(__fsub_rn(ix2, ix1), 0.0f);
  float dh = fmaxf(__fsub_rn(iy2, iy1), 0.0f);
  float inter = __fmul_rn(dw, dh);
  float uni = __fsub_rn(__fadd_rn(aarea, barea), inter);
  return (uni > 0.0f) && (inter > __fmul_rn(0.5f, uni));
}

#define CEXR(x, y, asc) { bool sw_ = (asc) ? ((x) > (y)) : ((x) < (y)); \
                          if (sw_) { u64 t_ = (x); (x) = (y); (y) = t_; } }

// Bitonic sort ascending over SZ u64 keys in LDS; 256-thread block.
__device__ __forceinline__ void bitonic_sort(u64* keys, int SZ, int tid) {
  for (int k = 2; k <= SZ; k <<= 1) {
    for (int j = k >> 1; j >= 4; j >>= 1) {
      for (int v = tid; v < (SZ >> 1); v += 256) {
        int i = ((v & ~(j - 1)) << 1) | (v & (j - 1));
        int p = i | j;
        bool asc = ((i & k) == 0);
        u64 a = keys[i], b = keys[p];
        bool sw = asc ? (a > b) : (a < b);
        if (sw) { keys[i] = b; keys[p] = a; }
      }
      __syncthreads();
    }
    if (tid < (SZ >> 2)) {
      ulonglong2* k2 = (ulonglong2*)keys;
      ulonglong2 lo = k2[tid * 2], hi = k2[tid * 2 + 1];
      u64 a = lo.x, b = lo.y, c = hi.x, d = hi.y;
      int i0 = tid << 2;
      if (k == 2) {
        CEXR(a, b, true); CEXR(c, d, false);
      } else {
        bool asc = ((i0 & k) == 0);
        CEXR(a, c, asc); CEXR(b, d, asc);  // j = 2
        CEXR(a, b, asc); CEXR(c, d, asc);  // j = 1
      }
      lo.x = a; lo.y = b; hi.x = c; hi.y = d;
      k2[tid * 2] = lo; k2[tid * 2 + 1] = hi;
    }
    __syncthreads();
  }
}

// Barrier-light suffix select over NB buckets (LDS or global hist):
// minimal suffix >= min(total, cap). sout: [0]=bucket [1]=sel [2]=above [3]=total.
template <int NB>
__device__ __forceinline__ void suffix_fast(const u32* hist, u32 cap, u32* wsum4, u32* sout) {
  const int tid = threadIdx.x, lane = tid & 63, w = tid >> 6;
  const int G = NB / 256;
  u32 v = 0;
  const int hb = tid * G;
#pragma unroll
  for (int t = 0; t < G; ++t) v += hist[hb + t];
  u32 s = v;
#pragma unroll
  for (int off = 1; off < 64; off <<= 1) {
    u32 t2 = __shfl_down(s, off);
    if (lane + off < 64) s += t2;
  }
  if (lane == 0) wsum4[w] = s;
  __syncthreads();
  u32 total = wsum4[0] + wsum4[1] + wsum4[2] + wsum4[3];
  u32 after = 0;
#pragma unroll
  for (int ww = 1; ww < 4; ++ww) if (ww > w) after += wsum4[ww];
  u32 inc = s + after;
  u32 exc = inc - v;
  if (tid == 0) {
    sout[3] = total;
    if (total == 0u) { sout[0] = 0u; sout[1] = 0u; sout[2] = 0u; }
  }
  u32 target = total < cap ? total : cap;
  if (total != 0u && inc >= target && exc < target) {  // exactly one thread
    u32 acc = exc;
    for (int u = hb + G - 1; u >= hb; --u) {
      acc += hist[u];
      if (acc >= target) { sout[0] = (u32)u; sout[1] = acc; sout[2] = acc - hist[u]; break; }
    }
  }
  __syncthreads();
}

// Transpose cls (B,N,C) -> colS (B,C,N). Block x==0 zeroes per-batch topk scratch.
__global__ __launch_bounds__(256) void k_tr(const float* __restrict__ cls,
                                            float* __restrict__ colS,
                                            u32* __restrict__ ghist,
                                            u32* __restrict__ gtail) {
  __shared__ float tile[NCLS * 65];
  const int tid = threadIdx.x;
  const int b = blockIdx.y;
  const int n0 = blockIdx.x * 64;
  if (blockIdx.x == 0) {
    for (int i = tid; i < NHB; i += 256) ghist[b * NHB + i] = 0u;
    if (tid == 0) gtail[b] = 0u;
  }
  const int rows = (NBOX - n0) < 64 ? (NBOX - n0) : 64;
  const float4* src4 = (const float4*)(cls + ((size_t)b * NBOX + n0) * NCLS);
  const int nq = rows * (NCLS / 4);
  for (int i = tid; i < nq; i += 256) {
    int rr = i / (NCLS / 4);
    int c4 = i - rr * (NCLS / 4);
    float4 v = src4[i];
    tile[(c4 * 4 + 0) * 65 + rr] = v.x;
    tile[(c4 * 4 + 1) * 65 + rr] = v.y;
    tile[(c4 * 4 + 2) * 65 + rr] = v.z;
    tile[(c4 * 4 + 3) * 65 + rr] = v.w;
  }
  __syncthreads();
  float4* dst4 = (float4*)colS;
  for (int i = tid; i < NCLS * 16; i += 256) {
    int c = i >> 4, nl = i & 15;
    if (nl * 4 < rows) {
      float4 v;
      v.x = tile[c * 65 + nl * 4 + 0];
      v.y = tile[c * 65 + nl * 4 + 1];
      v.z = tile[c * 65 + nl * 4 + 2];
      v.w = tile[c * 65 + nl * 4 + 3];
      dst4[(((size_t)b * NCLS + c) * NBOX + n0) / 4 + nl] = v;
    }
  }
}

// Zero scratch when transpose path is unavailable.
__global__ __launch_bounds__(256) void k_zero(u32* __restrict__ ghist,
                                              u32* __restrict__ gtail) {
  const int b = blockIdx.x;
  const int tid = threadIdx.x;
  for (int i = tid; i < NHB; i += 256) ghist[b * NHB + i] = 0u;
  if (tid == 0) gtail[b] = 0u;
}

template <int STRIDE>
__device__ __forceinline__ float4 load4s(const float* col, int q) {
  if (STRIDE == 1) return ((const float4*)col)[q];
  float4 v;
  v.x = col[(size_t)(q * 4 + 0) * STRIDE];
  v.y = col[(size_t)(q * 4 + 1) * STRIDE];
  v.z = col[(size_t)(q * 4 + 2) * STRIDE];
  v.w = col[(size_t)(q * 4 + 3) * STRIDE];
  return v;
}

// Phase A: single scan + speculative (>0.9) side buffer + flat 512-ULP histogram ->
// exact top-~TARGETK selection -> bitonic sort -> sorted keys to global.
template <int STRIDE>
__global__ __launch_bounds__(256) void k_sel(const float* __restrict__ scores,
                                             u64* __restrict__ keysBase, size_t kstride,
                                             int* __restrict__ selCnt,
                                             int* __restrict__ totCnt,
                                             int* __restrict__ flags) {
  __shared__ __align__(16) char smem[SPECCAP * 8 + NHB * 4 + CAP * 8];
  u64* side = (u64*)smem;
  u32* hist = (u32*)(smem + SPECCAP * 8);
  u64* keys = (u64*)(smem + SPECCAP * 8 + NHB * 4);
  __shared__ u32 wsum[4], selB[4], twave[4];
  __shared__ u32 s_scnt, s_cnt;

  const int tid = threadIdx.x;
  const int lane = tid & 63;
  const int w = tid >> 6;
  const u64 lmask = (1ull << lane) - 1ull;
  const int bc = blockIdx.x;
  const int b = bc / NCLS, c = bc % NCLS;
  const float* col = (STRIDE == 1) ? (scores + (size_t)bc * NBOX)
                                   : (scores + (size_t)b * NBOX * NCLS + c);

  for (int i = tid; i < NHB; i += 256) hist[i] = 0u;
  if (tid == 0) { s_scnt = 0u; s_cnt = 0u; }
  __syncthreads();

  u32 tailc = 0;
  for (int base = 0; base < NBOX / 4; base += 2048) {
    float4 v[8];
#pragma unroll
    for (int p = 0; p < 8; ++p) {
      int q = base + tid + (p << 8);
      if (q < NBOX / 4) v[p] = load4s<STRIDE>(col, q);
    }
#pragma unroll
    for (int p = 0; p < 8; ++p) {
      int q = base + tid + (p << 8);
      if (q < NBOX / 4) {
        float vv[4] = {v[p].x, v[p].y, v[p].z, v[p].w};
#pragma unroll
        for (int e = 0; e < 4; ++e) {
          float s = vv[e];
          bool spec = s > SPEC_THRF;
          if (s > SCORE_THR && !spec) ++tailc;
          u64 mb = __ballot(spec);
          if (mb) {
            u32 bs;
            if (lane == 0) bs = atomicAdd(&s_scnt, (u32)__popcll(mb));
            bs = __shfl(bs, 0);
            if (spec) {
              u32 bits = __float_as_uint(s);
              u32 pos = bs + (u32)__popcll(mb & lmask);
              if (pos < SPECCAP) side[pos] = ((u64)bits << 32) | (~(u32)(q * 4 + e));
              u32 h = (bits >> 9) - HB0;
              if (h > NHB - 1) h = NHB - 1;
              atomicAdd(&hist[h], 1u);
            }
          }
        }
      }
    }
  }
  u32 tr = tailc;
#pragma unroll
  for (int off = 1; off < 64; off <<= 1) tr += __shfl_down(tr, off);
  if (lane == 0) twave[w] = tr;
  __syncthreads();

  const u32 specCount = s_scnt;
  const u32 tailSum = twave[0] + twave[1] + twave[2] + twave[3];
  const u32 totalAll = specCount + tailSum;

  if (totalAll == 0u) {
    if (tid == 0) { selCnt[bc] = 0; totCnt[bc] = 0; flags[bc] = 0; }
    return;
  }
  const u32 target = totalAll < TARGETK ? totalAll : TARGETK;
  if (specCount < target || specCount > SPECCAP) {
    if (tid == 0) { selCnt[bc] = 0; totCnt[bc] = (int)totalAll; flags[bc] = 1; }
    return;
  }

  suffix_fast<NHB>(hist, target, wsum, selB);
  const u32 F0 = selB[0];
  const u32 selCount = selB[1];
  if (selCount > CAP) {
    if (tid == 0) { selCnt[bc] = 0; totCnt[bc] = (int)totalAll; flags[bc] = 1; }
    return;
  }

  const int iters = (int)((specCount + 255u) >> 8);
  for (int it2 = 0; it2 < iters; ++it2) {
    u32 idx = (u32)it2 * 256u + (u32)tid;
    bool act = idx < specCount;
    u64 key = act ? side[idx] : 0ull;
    u32 bits = (u32)(key >> 32);
    u32 h = (bits >> 9) - HB0;
    if (h > NHB - 1) h = NHB - 1;
    bool sel = act && (h >= F0);
    u64 ms = __ballot(sel);
    if (ms) {
      u32 bs;
      if (lane == 0) bs = atomicAdd(&s_cnt, (u32)__popcll(ms));
      bs = __shfl(bs, 0);
      if (sel) keys[bs + (u32)__popcll(ms & lmask)] = key;
    }
  }
  __syncthreads();
  for (int i = (int)selCount + tid; i < CAP; i += 256) keys[i] = 0ull;
  __syncthreads();

  bitonic_sort(keys, CAP, tid);

  u64* kout = keysBase + (size_t)bc * kstride;
  for (int i = tid; i < CAP; i += 256) kout[i] = keys[i];
  if (tid == 0) { selCnt[bc] = (int)selCount; totCnt[bc] = (int)totalAll; flags[bc] = 0; }
}

// Phase B: suppression-matrix NMS walk.
//  1) gather candidate boxes (descending order; candidate c <-> keys[CAP-1-c])
//  2) build bitmasks colM[wd][c] = {i in word wd, i<c : IoU(i,c)>0.5} — parallel,
//     no barriers/atomics; [wd][c] layout -> 8B lane stride (<=4-way bank alias);
//     variable loop bound (no wasted predicated iterations)
//  3) wave-0-only greedy walk over 64-chunks (kept mask in registers, no barriers)
// On success, also histograms kept scores into the per-batch global hist.
__global__ __launch_bounds__(512) void k_walk(const float* __restrict__ boxes,
                                              const u64* __restrict__ keysBase, size_t kstride,
                                              const int* __restrict__ selCnt,
                                              const int* __restrict__ totCnt,
                                              float* __restrict__ keptScore,
                                              int* __restrict__ keptN,
                                              int* __restrict__ keptCount,
                                              int* __restrict__ flags,
                                              u32* __restrict__ ghist,
                                              u32* __restrict__ gtail) {
  __shared__ __align__(16) char smem[47104];
  u64* keys = (u64*)smem;                   // [512]   @0
  float4* candbox = (float4*)(smem + 4096); // [512]   @4096
  float* carea = (float*)(smem + 12288);    // [512]   @12288
  u64* colM = (u64*)(smem + 14336);         // [8][512] @14336 (32 KB), [wd][c]
  __shared__ unsigned short keptIdx[MAXDET];
  __shared__ int s_kept;

  const int tid = threadIdx.x;
  const int lane = tid & 63;
  const int w = tid >> 6;
  const u64 lmask = (1ull << lane) - 1ull;
  const int bc = blockIdx.x;
  const int b = bc / NCLS;

  if (flags[bc] != 0) return;  // k_slow produces this problem exactly
  const u32 selCount = (u32)selCnt[bc];
  const u32 totalAll = (u32)totCnt[bc];

  const u64* kin = keysBase + (size_t)bc * kstride;
  for (int i = tid; i < CAP; i += 512) keys[i] = kin[i];
  if (tid == 0) s_kept = 0;
  __syncthreads();

  // Gather boxes in candidate order (c=0 highest score).
  for (int i = tid; i < (int)selCount; i += 512) {
    u32 n = ~((u32)keys[CAP - 1 - i]);
    float4 bb = ((const float4*)boxes)[(size_t)b * NBOX + n];
    candbox[i] = bb;
    carea[i] = __fmul_rn(__fsub_rn(bb.z, bb.x), __fsub_rn(bb.w, bb.y));
  }
  __syncthreads();

  // Matrix build: task -> (c = task&511, wd = task>>9). Each 64-task wave chunk has
  // uniform wd + consecutive c (b128 reads of candbox[c]); inner loop reads the
  // SAME candbox[i] on all lanes (broadcast). Variable trip count = max over lanes.
  for (int task = tid; task < CAP * 8; task += 512) {
    int c = task & (CAP - 1);
    int wd = task >> 9;
    u64 bits = 0ull;
    int jmax = c - (wd << 6);
    if (jmax > 64) jmax = 64;
    if (c < (int)selCount && jmax > 0) {
      float4 myb = candbox[c];
      float ma = carea[c];
      const int ibase = wd << 6;
#pragma unroll 4
      for (int jj = 0; jj < jmax; ++jj) {
        int i = ibase + jj;
        float4 ib = candbox[i];
        if (iou_sup_fast(ib.x, ib.y, ib.z, ib.w, carea[i],
                         myb.x, myb.y, myb.z, myb.w, ma))
          bits |= 1ull << jj;
      }
    }
    colM[wd * CAP + c] = bits;
  }
  __syncthreads();

  // Walk: wave 0 only, kept-mask K in registers (lane l<8 owns word l). No barriers.
  if (w == 0) {
    u64 Kreg = 0ull;
    int kept = 0;
    const u32 ntile = (selCount + 63u) >> 6;
    for (u32 t = 0; t < ntile && kept < MAXDET; ++t) {
      const int c = (int)(t * 64u) + lane;
      const bool valid = c < (int)selCount;
      u64 prior = 0ull;
      for (int wd = 0; wd < (int)t; ++wd) {
        u64 kw = __shfl(Kreg, wd);
        prior |= colM[wd * CAP + c] & kw;
      }
      u64 m = colM[(int)t * CAP + c];  // in-chunk suppressors (bits i<c only)
      u64 remaining = __ballot(valid && prior == 0ull);
      u64 keptmask = 0ull;
      const int room = MAXDET - kept;
      while (remaining != 0ull && (int)__popcll(keptmask) < room) {
        int j = __ffsll((long long)remaining) - 1;
        keptmask |= 1ull << j;
        remaining &= ~(1ull << j);
        u64 supj = __ballot(((m >> j) & 1ull) != 0ull);
        remaining &= ~supj;
      }
      if ((keptmask >> lane) & 1ull)
        keptIdx[kept + (int)__popcll(keptmask & lmask)] = (unsigned short)c;
      kept += (int)__popcll(keptmask);
      if (lane == (int)t) Kreg |= keptmask;
    }
    if (lane == 0) s_kept = kept;
  }
  __syncthreads();

  const int kept = s_kept;
  const bool exhausted = (kept < MAXDET && selCount < totalAll);
  for (int rr = tid; rr < MAXDET; rr += 512) {
    float sc = -INFINITY;
    int n = 0;
    if (rr < kept) {
      u64 key = keys[CAP - 1 - (int)keptIdx[rr]];
      sc = __uint_as_float((u32)(key >> 32));
      n = (int)(~((u32)key));
    }
    keptScore[bc * MAXDET + rr] = sc;
    keptN[bc * MAXDET + rr] = n;
  }
  if (tid == 0) {
    keptCount[bc] = kept;
    flags[bc] = exhausted ? 1 : 0;
  }
  if (!exhausted) {  // contribute kept scores to the per-batch top-k histogram
    for (int rr = tid; rr < kept; rr += 512) {
      float s = __uint_as_float((u32)(keys[CAP - 1 - (int)keptIdx[rr]] >> 32));
      if (s > SPEC_THRF) {
        u32 h = (__float_as_uint(s) >> 9) - HB0;
        if (h > NHB - 1) h = NHB - 1;
        atomicAdd(&ghist[b * NHB + h], 1u);
      } else {
        atomicAdd(&gtail[b], 1u);
      }
    }
  }
}

// Exact reference-style greedy NMS for flagged problems (expected: none fire).
// Also contributes its kept scores to the per-batch histogram.
__global__ __launch_bounds__(256) void k_slow(const float* __restrict__ boxes,
                                              const float* __restrict__ cls,
                                              float* __restrict__ keptScore,
                                              int* __restrict__ keptN,
                                              int* __restrict__ keptCount,
                                              const int* __restrict__ flags,
                                              u32* __restrict__ ghist,
                                              u32* __restrict__ gtail) {
  const int bc = blockIdx.x;
  if (flags[bc] != 1) return;
  const int tid = threadIdx.x;
  const int b = bc / NCLS, c = bc % NCLS;
  const float* col = cls + (size_t)b * NBOX * NCLS + c;
  __shared__ u32 sup[(NBOX + 31) / 32];
  __shared__ u64 red[256];
  __shared__ float4 sbx;
  __shared__ int s_kept;
  for (int i = tid; i < (NBOX + 31) / 32; i += 256) sup[i] = 0u;
  if (tid == 0) s_kept = 0;
  __syncthreads();
  for (int it = 0; it < MAXDET; ++it) {
    u64 best = 0ull;
    for (int n = tid; n < NBOX; n += 256) {
      if ((sup[n >> 5] >> (n & 31)) & 1u) continue;
      float s = col[(size_t)n * NCLS];
      if (s > SCORE_THR) {
        u64 key = ((u64)__float_as_uint(s) << 32) | (~(u32)n);
        if (key > best) best = key;
      }
    }
    red[tid] = best;
    __syncthreads();
    for (int off = 128; off > 0; off >>= 1) {
      if (tid < off) { u64 o = red[tid + off]; if (o > red[tid]) red[tid] = o; }
      __syncthreads();
    }
    u64 win = red[0];
    if (win == 0ull) break;
    u32 nw = ~((u32)win);
    if (tid == 0) {
      int k = s_kept;
      keptScore[bc * MAXDET + k] = __uint_as_float((u32)(win >> 32));
      keptN[bc * MAXDET + k] = (int)nw;
      s_kept = k + 1;
      sbx = ((const float4*)boxes)[(size_t)b * NBOX + nw];
    }
    __syncthreads();
    float4 bx = sbx;
    for (int n = tid; n < NBOX; n += 256) {
      float4 cb = ((const float4*)boxes)[(size_t)b * NBOX + n];
      if (iou_gt_half(bx.x, bx.y, bx.z, bx.w, cb.x, cb.y, cb.z, cb.w))
        atomicOr(&sup[n >> 5], 1u << (n & 31));
    }
    if (tid == 0) atomicOr(&sup[nw >> 5], 1u << (nw & 31));
    __syncthreads();
  }
  __syncthreads();
  const int kept = s_kept;
  for (int r = kept + tid; r < MAXDET; r += 256) {
    keptScore[bc * MAXDET + r] = -INFINITY;
    keptN[bc * MAXDET + r] = 0;
  }
  for (int rr = tid; rr < kept; rr += 256) {
    float s = keptScore[bc * MAXDET + rr];
    if (s > SPEC_THRF) {
      u32 h = (__float_as_uint(s) >> 9) - HB0;
      if (h > NHB - 1) h = NHB - 1;
      atomicAdd(&ghist[b * NHB + h], 1u);
    } else {
      atomicAdd(&gtail[b], 1u);
    }
  }
  if (tid == 0) keptCount[bc] = kept;
}

// Top-k + outputs: suffix-select from prebuilt per-batch hist -> compact scan ->
// bitonic-512 (exact lax.top_k ties) -> emit. Fallback: exact serial 80-way merge.
__global__ __launch_bounds__(256) void k_osort(const float* __restrict__ boxes,
                                               const float* __restrict__ rel,
                                               const float* __restrict__ keptScore,
                                               const int* __restrict__ keptN,
                                               const u32* __restrict__ ghist,
                                               const u32* __restrict__ gtail,
                                               float* __restrict__ out) {
  __shared__ u64 keys[1024];
  __shared__ u32 wsum[4], selB[4];
  __shared__ u32 s_cnt;
  const int tid = threadIdx.x;
  const int lane = tid & 63;
  const u64 lmask = (1ull << lane) - 1ull;
  const int b = blockIdx.x;
  const float4* ks4 = (const float4*)(keptScore + (size_t)b * NTOT);

  if (tid == 0) s_cnt = 0u;
  suffix_fast<NHB>(ghist + (size_t)b * NHB, (u32)MAXDET, wsum, selB);
  const u32 specTotal = selB[3];
  const u32 totalAll = specTotal + gtail[b];
  const u32 target = totalAll < (u32)MAXDET ? totalAll : (u32)MAXDET;
  const u32 F0 = selB[0];
  const u32 selSpec = selB[1];
  const bool fast = (totalAll != 0u) && (specTotal >= target) && (selSpec <= (u32)CAP);
  int SZ = CAP;

  if (totalAll != 0u) {
    if (fast) {
      for (int base = 0; base < NTOT / 4; base += 2048) {
        float4 v[8];
#pragma unroll
        for (int p = 0; p < 8; ++p) {
          int q = base + tid + (p << 8);
          if (q < NTOT / 4) v[p] = ks4[q];
        }
#pragma unroll
        for (int p = 0; p < 8; ++p) {
          int q = base + tid + (p << 8);
          if (q < NTOT / 4) {
            float vv[4] = {v[p].x, v[p].y, v[p].z, v[p].w};
#pragma unroll
            for (int e = 0; e < 4; ++e) {
              float s = vv[e];
              bool sel = false;
              u32 bits = 0;
              if (s > SPEC_THRF) {
                bits = __float_as_uint(s);
                u32 h = (bits >> 9) - HB0;
                if (h > NHB - 1) h = NHB - 1;
                sel = (h >= F0);
              }
              u64 ms = __ballot(sel);
              if (ms) {
                u32 bs;
                if (lane == 0) bs = atomicAdd(&s_cnt, (u32)__popcll(ms));
                bs = __shfl(bs, 0);
                if (sel)
                  keys[bs + (u32)__popcll(ms & lmask)] =
                      ((u64)bits << 32) | (~(u32)(q * 4 + e));
              }
            }
          }
        }
      }
      __syncthreads();
      for (int i = (int)selSpec + tid; i < CAP; i += 256) keys[i] = 0ull;
      __syncthreads();
      bitonic_sort(keys, CAP, tid);
      SZ = CAP;
    } else {
      // Exact fallback: serial 80-way merge of the sorted per-class lists.
      if (tid < 64) {
        const int c0 = lane, c1 = 64 + lane;
        const bool has1 = (c1 < NCLS);
        const float* ls0 = keptScore + ((size_t)b * NCLS + c0) * MAXDET;
        const float* ls1 = keptScore + ((size_t)b * NCLS + (has1 ? c1 : c0)) * MAXDET;
        int h0 = 0, h1 = 0;
        float v0 = ls0[0], w0v = ls0[1];
        float v1 = has1 ? ls1[0] : -INFINITY;
        float w1v = has1 ? ls1[1] : -INFINITY;
        for (int r = 0; r < (int)target; ++r) {
          float bs; int bcl;
          if (has1 && v1 > v0) { bs = v1; bcl = c1; } else { bs = v0; bcl = c0; }
#pragma unroll
          for (int off = 32; off > 0; off >>= 1) {
            float os = __shfl_xor(bs, off);
            int oc = __shfl_xor(bcl, off);
            if (os > bs || (os == bs && oc < bcl)) { bs = os; bcl = oc; }
          }
          if (bcl == c0) {
            keys[1023 - r] = ((u64)__float_as_uint(bs) << 32) | (~(u32)(c0 * MAXDET + h0));
            ++h0; v0 = w0v; w0v = (h0 + 1 < MAXDET) ? ls0[h0 + 1] : -INFINITY;
          } else if (has1 && bcl == c1) {
            keys[1023 - r] = ((u64)__float_as_uint(bs) << 32) | (~(u32)(c1 * MAXDET + h1));
            ++h1; v1 = w1v; w1v = (h1 + 1 < MAXDET) ? ls1[h1 + 1] : -INFINITY;
          }
        }
      }
      __syncthreads();
      SZ = 1024;
    }
  }

  for (int r = tid; r < MAXDET; r += 256) {
    const bool valid = (u32)r < target;
    float s = -1.0f, pm = -1.0f, pl = -1.0f, cl = -1.0f;
    float4 ob; ob.x = ob.y = ob.z = ob.w = -1.0f;
    if (valid) {
      u64 key = keys[SZ - 1 - r];
      u32 fp = ~((u32)key);
      int c = (int)(fp / MAXDET);
      int slot = (int)(fp - (u32)c * MAXDET);
      int n = keptN[((size_t)b * NCLS + c) * MAXDET + slot];
      s = __uint_as_float((u32)(key >> 32));
      cl = (float)c;
      size_t nb = (size_t)b * NBOX + (u32)n;
      ob = ((const float4*)boxes)[nb];
      const float* rp = rel + nb * NREL;
      float vr[NREL];
#pragma unroll
      for (int p = 0; p < NREL; ++p) vr[p] = rp[p];  // all loads in flight
      float best = vr[0]; int bi = 0;
#pragma unroll
      for (int p = 1; p < NREL; ++p) { if (vr[p] > best) { best = vr[p]; bi = p; } }
      pm = best; pl = (float)bi;
    }
    ((float4*)out)[(size_t)b * MAXDET + r] = ob;
    const int sbase = NBATCH * MAXDET * 4;
    out[sbase + b * MAXDET + r] = s;
    out[sbase + NBATCH * MAXDET + b * MAXDET + r] = cl;
    out[sbase + 2 * NBATCH * MAXDET + b * MAXDET + r] = pm;
    out[sbase + 3 * NBATCH * MAXDET + b * MAXDET + r] = pl;
  }
}

extern "C" void kernel_launch(void* const* d_in, const int* in_sizes, int n_in,
                              void* d_out, int out_size, void* d_ws, size_t ws_size,
                              hipStream_t stream) {
  (void)in_sizes; (void)n_in; (void)out_size;
  const float* boxes = (const float*)d_in[0];
  const float* cls   = (const float*)d_in[1];
  const float* rel   = (const float*)d_in[2];
  float* out = (float*)d_out;
  char* ws = (char*)d_ws;

  const size_t trBytes = (size_t)NBATCH * NCLS * NBOX * 4;  // 51.2 MB
  const size_t NP = NBATCH * NCLS;                          // 640 problems

  float* colS = (float*)ws;
  size_t off = 0;
  const size_t oKeptScore = off; off += NP * MAXDET * 4;
  const size_t oKeptN     = off; off += NP * MAXDET * 4;
  const size_t oKeptCount = off; off += NP * 4;
  const size_t oFlags     = off; off += NP * 4;
  const size_t oSelCnt    = off; off += NP * 4;
  const size_t oTotCnt    = off; off += NP * 4;
  const size_t oKeysSep   = off; off += NP * CAP * 8;
  const size_t oGhist     = off; off += (size_t)NBATCH * NHB * 4;
  const size_t oGtail     = off; off += NBATCH * 4;
  const size_t kbaseBytes = off;

  const bool useTr = ws_size >= trBytes + kbaseBytes;
  char* kbase = useTr ? (ws + trBytes) : ws;

  float* keptScore = (float*)(kbase + oKeptScore);
  int* keptN = (int*)(kbase + oKeptN);
  int* keptCount = (int*)(kbase + oKeptCount);
  int* flags = (int*)(kbase + oFlags);
  int* selCnt = (int*)(kbase + oSelCnt);
  int* totCnt = (int*)(kbase + oTotCnt);
  u64* keysSep = (u64*)(kbase + oKeysSep);
  u32* ghist = (u32*)(kbase + oGhist);
  u32* gtail = (u32*)(kbase + oGtail);

  u64* keysBase = useTr ? (u64*)colS : keysSep;
  const size_t kstride = useTr ? (size_t)(NBOX / 2) : (size_t)CAP;

  if (useTr) {
    k_tr<<<dim3((NBOX + 63) / 64, NBATCH), 256, 0, stream>>>(cls, colS, ghist, gtail);
    k_sel<1><<<NP, 256, 0, stream>>>(colS, keysBase, kstride, selCnt, totCnt, flags);
  } else {
    k_zero<<<NBATCH, 256, 0, stream>>>(ghist, gtail);
    k_sel<NCLS><<<NP, 256, 0, stream>>>(cls, keysBase, kstride, selCnt, totCnt, flags);
  }
  k_walk<<<NP, 512, 0, stream>>>(boxes, keysBase, kstride, selCnt, totCnt,
                                 keptScore, keptN, keptCount, flags, ghist, gtail);
  k_slow<<<NP, 256, 0, stream>>>(boxes, cls, keptScore, keptN, keptCount, flags,
                                 ghist, gtail);
  k_osort<<<NBATCH, 256, 0, stream>>>(boxes, rel, keptScore, keptN, ghist, gtail, out);
}

// Round 12
// 168.743 us; speedup vs baseline: 1.1338x; 1.0448x over previous
//
#include <hip/hip_runtime.h>
#include <hip/hip_bf16.h>
#include <math.h>

#define NBATCH 8
#define NBOX   20000
#define NCLS   80
#define NREL   51
#define MAXDET 300
#define NTOT   (NCLS * MAXDET)      // 24000
#define CAP    512                  // sorted-key buffer (pow2 for bitonic)
#define CAPM   384                  // NMS candidate matrix size (6 chunks of 64)
#define SPECCAP 2560
#define NHB    3328
#define HB0    (0x3F666666u >> 9)   // bucket base = bits(0.9f) >> 9
#define TARGETK 360u
#define SCORE_THR 0.05f
#define SPEC_THRF 0.9f

typedef unsigned long long u64;
typedef unsigned int u32;

// IoU > 0.5, explicit IEEE div (k_slow only).
__device__ __forceinline__ bool iou_sup(float ax1, float ay1, float ax2, float ay2, float aarea,
                                        float bx1, float by1, float bx2, float by2, float barea) {
  float ix1 = fmaxf(ax1, bx1);
  float iy1 = fmaxf(ay1, by1);
  float ix2 = fminf(ax2, bx2);
  float iy2 = fminf(ay2, by2);
  float dw = fmaxf(__fsub_rn(ix2, ix1), 0.0f);
  float dh = fmaxf(__fsub_rn(iy2, iy1), 0.0f);
  float inter = __fmul_rn(dw, dh);
  float uni = __fsub_rn(__fadd_rn(aarea, barea), inter);
  if (!(uni > 0.0f)) return false;
  return __fdiv_rn(inter, uni) > 0.5f;
}

__device__ __forceinline__ bool iou_gt_half(float ax1, float ay1, float ax2, float ay2,
                                            float bx1, float by1, float bx2, float by2) {
  float aa = __fmul_rn(__fsub_rn(ax2, ax1), __fsub_rn(ay2, ay1));
  float ab = __fmul_rn(__fsub_rn(bx2, bx1), __fsub_rn(by2, by1));
  return iou_sup(ax1, ay1, ax2, ay2, aa, bx1, by1, bx2, by2, ab);
}

// Bit-exact div-free IoU>0.5 in PURE f32:
//   rn32(inter/uni) > 0.5  ⟺  inter/uni > 0.5(1+2^-24)   (tie->even = 0.5)
//   f32 test inter > 0.5*uni differs only if a float inter lies in
//   (0.5uni, 0.5uni(1+2^-24)] — impossible: succ(a) = a(1+2^-23/m), m<2.
__device__ __forceinline__ bool iou_sup_fast(float ax1, float ay1, float ax2, float ay2,
                                             float aarea, float bx1, float by1, float bx2,
                                             float by2, float barea) {
  float ix1 = fmaxf(ax1, bx1);
  float iy1 = fmaxf(ay1, by1);
  float ix2 = fminf(ax2, bx2);
  float iy2 = fminf(ay2, by2);
  float dw = fmaxf(__fsub_rn(ix2, ix1), 0.0f);
  float dh = fmaxf(__fsub_rn(iy2, iy1), 0.0f);
  float inter = __fmul_rn(dw, dh);
  float uni = __fsub_rn(__fadd_rn(aarea, barea), inter);
  return (uni > 0.0f) && (inter > __fmul_rn(0.5f, uni));
}

__device__ __forceinline__ float rdlane(float v, int l) {
  return __uint_as_float(__builtin_amdgcn_readlane(__float_as_uint(v), l));
}

#define CEXR(x, y, asc) { bool sw_ = (asc) ? ((x) > (y)) : ((x) < (y)); \
                          if (sw_) { u64 t_ = (x); (x) = (y); (y) = t_; } }

// Bitonic sort ascending over SZ u64 keys in LDS; 256-thread block.
__device__ __forceinline__ void bitonic_sort(u64* keys, int SZ, int tid) {
  for (int k = 2; k <= SZ; k <<= 1) {
    for (int j = k >> 1; j >= 4; j >>= 1) {
      for (int v = tid; v < (SZ >> 1); v += 256) {
        int i = ((v & ~(j - 1)) << 1) | (v & (j - 1));
        int p = i | j;
        bool asc = ((i & k) == 0);
        u64 a = keys[i], b = keys[p];
        bool sw = asc ? (a > b) : (a < b);
        if (sw) { keys[i] = b; keys[p] = a; }
      }
      __syncthreads();
    }
    if (tid < (SZ >> 2)) {
      ulonglong2* k2 = (ulonglong2*)keys;
      ulonglong2 lo = k2[tid * 2], hi = k2[tid * 2 + 1];
      u64 a = lo.x, b = lo.y, c = hi.x, d = hi.y;
      int i0 = tid << 2;
      if (k == 2) {
        CEXR(a, b, true); CEXR(c, d, false);
      } else {
        bool asc = ((i0 & k) == 0);
        CEXR(a, c, asc); CEXR(b, d, asc);  // j = 2
        CEXR(a, b, asc); CEXR(c, d, asc);  // j = 1
      }
      lo.x = a; lo.y = b; hi.x = c; hi.y = d;
      k2[tid * 2] = lo; k2[tid * 2 + 1] = hi;
    }
    __syncthreads();
  }
}

// Barrier-light suffix select over NB buckets (LDS or global hist):
// minimal suffix >= min(total, cap). sout: [0]=bucket [1]=sel [2]=above [3]=total.
template <int NB>
__device__ __forceinline__ void suffix_fast(const u32* hist, u32 cap, u32* wsum4, u32* sout) {
  const int tid = threadIdx.x, lane = tid & 63, w = tid >> 6;
  const int G = NB / 256;
  u32 v = 0;
  const int hb = tid * G;
#pragma unroll
  for (int t = 0; t < G; ++t) v += hist[hb + t];
  u32 s = v;
#pragma unroll
  for (int off = 1; off < 64; off <<= 1) {
    u32 t2 = __shfl_down(s, off);
    if (lane + off < 64) s += t2;
  }
  if (lane == 0) wsum4[w] = s;
  __syncthreads();
  u32 total = wsum4[0] + wsum4[1] + wsum4[2] + wsum4[3];
  u32 after = 0;
#pragma unroll
  for (int ww = 1; ww < 4; ++ww) if (ww > w) after += wsum4[ww];
  u32 inc = s + after;
  u32 exc = inc - v;
  if (tid == 0) {
    sout[3] = total;
    if (total == 0u) { sout[0] = 0u; sout[1] = 0u; sout[2] = 0u; }
  }
  u32 target = total < cap ? total : cap;
  if (total != 0u && inc >= target && exc < target) {  // exactly one thread
    u32 acc = exc;
    for (int u = hb + G - 1; u >= hb; --u) {
      acc += hist[u];
      if (acc >= target) { sout[0] = (u32)u; sout[1] = acc; sout[2] = acc - hist[u]; break; }
    }
  }
  __syncthreads();
}

// Transpose cls (B,N,C) -> colS (B,C,N). Block x==0 zeroes per-batch topk scratch.
__global__ __launch_bounds__(256) void k_tr(const float* __restrict__ cls,
                                            float* __restrict__ colS,
                                            u32* __restrict__ ghist,
                                            u32* __restrict__ gtail) {
  __shared__ float tile[NCLS * 65];
  const int tid = threadIdx.x;
  const int b = blockIdx.y;
  const int n0 = blockIdx.x * 64;
  if (blockIdx.x == 0) {
    for (int i = tid; i < NHB; i += 256) ghist[b * NHB + i] = 0u;
    if (tid == 0) gtail[b] = 0u;
  }
  const int rows = (NBOX - n0) < 64 ? (NBOX - n0) : 64;
  const float4* src4 = (const float4*)(cls + ((size_t)b * NBOX + n0) * NCLS);
  const int nq = rows * (NCLS / 4);
  for (int i = tid; i < nq; i += 256) {
    int rr = i / (NCLS / 4);
    int c4 = i - rr * (NCLS / 4);
    float4 v = src4[i];
    tile[(c4 * 4 + 0) * 65 + rr] = v.x;
    tile[(c4 * 4 + 1) * 65 + rr] = v.y;
    tile[(c4 * 4 + 2) * 65 + rr] = v.z;
    tile[(c4 * 4 + 3) * 65 + rr] = v.w;
  }
  __syncthreads();
  float4* dst4 = (float4*)colS;
  for (int i = tid; i < NCLS * 16; i += 256) {
    int c = i >> 4, nl = i & 15;
    if (nl * 4 < rows) {
      float4 v;
      v.x = tile[c * 65 + nl * 4 + 0];
      v.y = tile[c * 65 + nl * 4 + 1];
      v.z = tile[c * 65 + nl * 4 + 2];
      v.w = tile[c * 65 + nl * 4 + 3];
      dst4[(((size_t)b * NCLS + c) * NBOX + n0) / 4 + nl] = v;
    }
  }
}

// Zero scratch when transpose path is unavailable.
__global__ __launch_bounds__(256) void k_zero(u32* __restrict__ ghist,
                                              u32* __restrict__ gtail) {
  const int b = blockIdx.x;
  const int tid = threadIdx.x;
  for (int i = tid; i < NHB; i += 256) ghist[b * NHB + i] = 0u;
  if (tid == 0) gtail[b] = 0u;
}

template <int STRIDE>
__device__ __forceinline__ float4 load4s(const float* col, int q) {
  if (STRIDE == 1) return ((const float4*)col)[q];
  float4 v;
  v.x = col[(size_t)(q * 4 + 0) * STRIDE];
  v.y = col[(size_t)(q * 4 + 1) * STRIDE];
  v.z = col[(size_t)(q * 4 + 2) * STRIDE];
  v.w = col[(size_t)(q * 4 + 3) * STRIDE];
  return v;
}

// Phase A: single scan + speculative (>0.9) side buffer + flat 512-ULP histogram ->
// exact top-~TARGETK selection -> bitonic sort -> sorted keys to global.
template <int STRIDE>
__global__ __launch_bounds__(256) void k_sel(const float* __restrict__ scores,
                                             u64* __restrict__ keysBase, size_t kstride,
                                             int* __restrict__ selCnt,
                                             int* __restrict__ totCnt,
                                             int* __restrict__ flags) {
  __shared__ __align__(16) char smem[SPECCAP * 8 + NHB * 4 + CAP * 8];
  u64* side = (u64*)smem;
  u32* hist = (u32*)(smem + SPECCAP * 8);
  u64* keys = (u64*)(smem + SPECCAP * 8 + NHB * 4);
  __shared__ u32 wsum[4], selB[4], twave[4];
  __shared__ u32 s_scnt, s_cnt;

  const int tid = threadIdx.x;
  const int lane = tid & 63;
  const int w = tid >> 6;
  const u64 lmask = (1ull << lane) - 1ull;
  const int bc = blockIdx.x;
  const int b = bc / NCLS, c = bc % NCLS;
  const float* col = (STRIDE == 1) ? (scores + (size_t)bc * NBOX)
                                   : (scores + (size_t)b * NBOX * NCLS + c);

  for (int i = tid; i < NHB; i += 256) hist[i] = 0u;
  if (tid == 0) { s_scnt = 0u; s_cnt = 0u; }
  __syncthreads();

  u32 tailc = 0;
  for (int base = 0; base < NBOX / 4; base += 2048) {
    float4 v[8];
#pragma unroll
    for (int p = 0; p < 8; ++p) {
      int q = base + tid + (p << 8);
      if (q < NBOX / 4) v[p] = load4s<STRIDE>(col, q);
    }
#pragma unroll
    for (int p = 0; p < 8; ++p) {
      int q = base + tid + (p << 8);
      if (q < NBOX / 4) {
        float vv[4] = {v[p].x, v[p].y, v[p].z, v[p].w};
#pragma unroll
        for (int e = 0; e < 4; ++e) {
          float s = vv[e];
          bool spec = s > SPEC_THRF;
          if (s > SCORE_THR && !spec) ++tailc;
          u64 mb = __ballot(spec);
          if (mb) {
            u32 bs;
            if (lane == 0) bs = atomicAdd(&s_scnt, (u32)__popcll(mb));
            bs = __shfl(bs, 0);
            if (spec) {
              u32 bits = __float_as_uint(s);
              u32 pos = bs + (u32)__popcll(mb & lmask);
              if (pos < SPECCAP) side[pos] = ((u64)bits << 32) | (~(u32)(q * 4 + e));
              u32 h = (bits >> 9) - HB0;
              if (h > NHB - 1) h = NHB - 1;
              atomicAdd(&hist[h], 1u);
            }
          }
        }
      }
    }
  }
  u32 tr = tailc;
#pragma unroll
  for (int off = 1; off < 64; off <<= 1) tr += __shfl_down(tr, off);
  if (lane == 0) twave[w] = tr;
  __syncthreads();

  const u32 specCount = s_scnt;
  const u32 tailSum = twave[0] + twave[1] + twave[2] + twave[3];
  const u32 totalAll = specCount + tailSum;

  if (totalAll == 0u) {
    if (tid == 0) { selCnt[bc] = 0; totCnt[bc] = 0; flags[bc] = 0; }
    return;
  }
  const u32 target = totalAll < TARGETK ? totalAll : TARGETK;
  if (specCount < target || specCount > SPECCAP) {
    if (tid == 0) { selCnt[bc] = 0; totCnt[bc] = (int)totalAll; flags[bc] = 1; }
    return;
  }

  suffix_fast<NHB>(hist, target, wsum, selB);
  const u32 F0 = selB[0];
  const u32 selCount = selB[1];
  if (selCount > (u32)CAPM) {  // beyond matrix capacity: exact slow path
    if (tid == 0) { selCnt[bc] = 0; totCnt[bc] = (int)totalAll; flags[bc] = 1; }
    return;
  }

  const int iters = (int)((specCount + 255u) >> 8);
  for (int it2 = 0; it2 < iters; ++it2) {
    u32 idx = (u32)it2 * 256u + (u32)tid;
    bool act = idx < specCount;
    u64 key = act ? side[idx] : 0ull;
    u32 bits = (u32)(key >> 32);
    u32 h = (bits >> 9) - HB0;
    if (h > NHB - 1) h = NHB - 1;
    bool sel = act && (h >= F0);
    u64 ms = __ballot(sel);
    if (ms) {
      u32 bs;
      if (lane == 0) bs = atomicAdd(&s_cnt, (u32)__popcll(ms));
      bs = __shfl(bs, 0);
      if (sel) keys[bs + (u32)__popcll(ms & lmask)] = key;
    }
  }
  __syncthreads();
  for (int i = (int)selCount + tid; i < CAP; i += 256) keys[i] = 0ull;
  __syncthreads();

  bitonic_sort(keys, CAP, tid);

  u64* kout = keysBase + (size_t)bc * kstride;
  for (int i = tid; i < CAP; i += 256) kout[i] = keys[i];
  if (tid == 0) { selCnt[bc] = (int)selCount; totCnt[bc] = (int)totalAll; flags[bc] = 0; }
}

// Phase B: suppression-matrix NMS walk, register-resident build.
//  1) gather candidate boxes (descending order; candidate c <-> keys[CAP-1-c])
//  2) build colM[wd][c] = {i in word wd, i<c : IoU(i,c)>0.5}: wave-task = chunk
//     pair (cc>=wd); lane holds its column box AND its row box in REGISTERS;
//     row j is broadcast per iteration via v_readlane (VALU, not LDS pipe).
//     ~5 LDS ops per 64x64 pair instead of ~128.
//  3) wave-0-only greedy walk over 64-chunks (kept mask in registers, no barriers)
// On success, also histograms kept scores into the per-batch global hist.
__global__ __launch_bounds__(512) void k_walk(const float* __restrict__ boxes,
                                              const u64* __restrict__ keysBase, size_t kstride,
                                              const int* __restrict__ selCnt,
                                              const int* __restrict__ totCnt,
                                              float* __restrict__ keptScore,
                                              int* __restrict__ keptN,
                                              int* __restrict__ keptCount,
                                              int* __restrict__ flags,
                                              u32* __restrict__ ghist,
                                              u32* __restrict__ gtail) {
  __shared__ __align__(16) char smem[30208];
  u64* keys = (u64*)smem;                    // [512]        @0
  float4* candbox = (float4*)(smem + 4096);  // [CAPM]       @4096
  float* carea = (float*)(smem + 10240);     // [CAPM]       @10240
  u64* colM = (u64*)(smem + 11776);          // [6][CAPM]    @11776 (18 KB)
  __shared__ unsigned short keptIdx[MAXDET];
  __shared__ int s_kept;

  const int tid = threadIdx.x;
  const int lane = tid & 63;
  const int w = tid >> 6;
  const u64 lmask = (1ull << lane) - 1ull;
  const int bc = blockIdx.x;
  const int b = bc / NCLS;

  if (flags[bc] != 0) return;  // k_slow produces this problem exactly
  const u32 selCount = (u32)selCnt[bc];   // <= CAPM
  const u32 totalAll = (u32)totCnt[bc];

  const u64* kin = keysBase + (size_t)bc * kstride;
  for (int i = tid; i < CAP; i += 512) keys[i] = kin[i];
  if (tid == 0) s_kept = 0;
  __syncthreads();

  // Gather boxes in candidate order (c=0 highest score).
  for (int i = tid; i < (int)selCount; i += 512) {
    u32 n = ~((u32)keys[CAP - 1 - i]);
    float4 bb = ((const float4*)boxes)[(size_t)b * NBOX + n];
    candbox[i] = bb;
    carea[i] = __fmul_rn(__fsub_rn(bb.z, bb.x), __fsub_rn(bb.w, bb.y));
  }
  __syncthreads();

  // Matrix build: 21 chunk-pairs (cc>=wd), round-robin over 8 waves.
  for (int p = w; p < 21; p += 8) {
    int cc = 0;
    while ((cc + 1) * (cc + 2) / 2 <= p) ++cc;   // decode pair index -> (cc, wd)
    int wd = p - cc * (cc + 1) / 2;
    const int c = (cc << 6) + lane;
    const int rbase = wd << 6;
    float4 myc = candbox[c];
    float mya = carea[c];
    float4 rb = candbox[rbase + lane];
    float ra = carea[rbase + lane];
    const bool colvalid = c < (int)selCount;
    u64 bits = 0ull;
#pragma unroll 4
    for (int jj = 0; jj < 64; ++jj) {
      float bx1 = rdlane(rb.x, jj);
      float by1 = rdlane(rb.y, jj);
      float bx2 = rdlane(rb.z, jj);
      float by2 = rdlane(rb.w, jj);
      float ba  = rdlane(ra, jj);
      int i = rbase + jj;
      if (colvalid && i < c &&
          iou_sup_fast(bx1, by1, bx2, by2, ba, myc.x, myc.y, myc.z, myc.w, mya))
        bits |= 1ull << jj;
    }
    colM[wd * CAPM + c] = bits;
  }
  __syncthreads();

  // Walk: wave 0 only, kept-mask K in registers (lane t<6 owns word t). No barriers.
  if (w == 0) {
    u64 Kreg = 0ull;
    int kept = 0;
    const u32 ntile = (selCount + 63u) >> 6;
    for (u32 t = 0; t < ntile && kept < MAXDET; ++t) {
      const int c = (int)(t * 64u) + lane;
      const bool valid = c < (int)selCount;
      u64 prior = 0ull;
      for (int wd = 0; wd < (int)t; ++wd) {
        u64 kw = __shfl(Kreg, wd);
        prior |= colM[wd * CAPM + c] & kw;
      }
      u64 m = colM[(int)t * CAPM + c];  // in-chunk suppressors (bits i<c only)
      u64 remaining = __ballot(valid && prior == 0ull);
      u64 keptmask = 0ull;
      const int room = MAXDET - kept;
      while (remaining != 0ull && (int)__popcll(keptmask) < room) {
        int j = __ffsll((long long)remaining) - 1;
        keptmask |= 1ull << j;
        remaining &= ~(1ull << j);
        u64 supj = __ballot(((m >> j) & 1ull) != 0ull);
        remaining &= ~supj;
      }
      if ((keptmask >> lane) & 1ull)
        keptIdx[kept + (int)__popcll(keptmask & lmask)] = (unsigned short)c;
      kept += (int)__popcll(keptmask);
      if (lane == (int)t) Kreg |= keptmask;
    }
    if (lane == 0) s_kept = kept;
  }
  __syncthreads();

  const int kept = s_kept;
  const bool exhausted = (kept < MAXDET && selCount < totalAll);
  for (int rr = tid; rr < MAXDET; rr += 512) {
    float sc = -INFINITY;
    int n = 0;
    if (rr < kept) {
      u64 key = keys[CAP - 1 - (int)keptIdx[rr]];
      sc = __uint_as_float((u32)(key >> 32));
      n = (int)(~((u32)key));
    }
    keptScore[bc * MAXDET + rr] = sc;
    keptN[bc * MAXDET + rr] = n;
  }
  if (tid == 0) {
    keptCount[bc] = kept;
    flags[bc] = exhausted ? 1 : 0;
  }
  if (!exhausted) {  // contribute kept scores to the per-batch top-k histogram
    for (int rr = tid; rr < kept; rr += 512) {
      float s = __uint_as_float((u32)(keys[CAP - 1 - (int)keptIdx[rr]] >> 32));
      if (s > SPEC_THRF) {
        u32 h = (__float_as_uint(s) >> 9) - HB0;
        if (h > NHB - 1) h = NHB - 1;
        atomicAdd(&ghist[b * NHB + h], 1u);
      } else {
        atomicAdd(&gtail[b], 1u);
      }
    }
  }
}

// Exact reference-style greedy NMS for flagged problems (expected: none fire).
// Also contributes its kept scores to the per-batch histogram.
__global__ __launch_bounds__(256) void k_slow(const float* __restrict__ boxes,
                                              const float* __restrict__ cls,
                                              float* __restrict__ keptScore,
                                              int* __restrict__ keptN,
                                              int* __restrict__ keptCount,
                                              const int* __restrict__ flags,
                                              u32* __restrict__ ghist,
                                              u32* __restrict__ gtail) {
  const int bc = blockIdx.x;
  if (flags[bc] != 1) return;
  const int tid = threadIdx.x;
  const int b = bc / NCLS, c = bc % NCLS;
  const float* col = cls + (size_t)b * NBOX * NCLS + c;
  __shared__ u32 sup[(NBOX + 31) / 32];
  __shared__ u64 red[256];
  __shared__ float4 sbx;
  __shared__ int s_kept;
  for (int i = tid; i < (NBOX + 31) / 32; i += 256) sup[i] = 0u;
  if (tid == 0) s_kept = 0;
  __syncthreads();
  for (int it = 0; it < MAXDET; ++it) {
    u64 best = 0ull;
    for (int n = tid; n < NBOX; n += 256) {
      if ((sup[n >> 5] >> (n & 31)) & 1u) continue;
      float s = col[(size_t)n * NCLS];
      if (s > SCORE_THR) {
        u64 key = ((u64)__float_as_uint(s) << 32) | (~(u32)n);
        if (key > best) best = key;
      }
    }
    red[tid] = best;
    __syncthreads();
    for (int off = 128; off > 0; off >>= 1) {
      if (tid < off) { u64 o = red[tid + off]; if (o > red[tid]) red[tid] = o; }
      __syncthreads();
    }
    u64 win = red[0];
    if (win == 0ull) break;
    u32 nw = ~((u32)win);
    if (tid == 0) {
      int k = s_kept;
      keptScore[bc * MAXDET + k] = __uint_as_float((u32)(win >> 32));
      keptN[bc * MAXDET + k] = (int)nw;
      s_kept = k + 1;
      sbx = ((const float4*)boxes)[(size_t)b * NBOX + nw];
    }
    __syncthreads();
    float4 bx = sbx;
    for (int n = tid; n < NBOX; n += 256) {
      float4 cb = ((const float4*)boxes)[(size_t)b * NBOX + n];
      if (iou_gt_half(bx.x, bx.y, bx.z, bx.w, cb.x, cb.y, cb.z, cb.w))
        atomicOr(&sup[n >> 5], 1u << (n & 31));
    }
    if (tid == 0) atomicOr(&sup[nw >> 5], 1u << (nw & 31));
    __syncthreads();
  }
  __syncthreads();
  const int kept = s_kept;
  for (int r = kept + tid; r < MAXDET; r += 256) {
    keptScore[bc * MAXDET + r] = -INFINITY;
    keptN[bc * MAXDET + r] = 0;
  }
  for (int rr = tid; rr < kept; rr += 256) {
    float s = keptScore[bc * MAXDET + rr];
    if (s > SPEC_THRF) {
      u32 h = (__float_as_uint(s) >> 9) - HB0;
      if (h > NHB - 1) h = NHB - 1;
      atomicAdd(&ghist[b * NHB + h], 1u);
    } else {
      atomicAdd(&gtail[b], 1u);
    }
  }
  if (tid == 0) keptCount[bc] = kept;
}

// Top-k + outputs: suffix-select from prebuilt per-batch hist -> compact scan ->
// bitonic-512 (exact lax.top_k ties) -> emit. Fallback: exact serial 80-way merge.
__global__ __launch_bounds__(256) void k_osort(const float* __restrict__ boxes,
                                               const float* __restrict__ rel,
                                               const float* __restrict__ keptScore,
                                               const int* __restrict__ keptN,
                                               const u32* __restrict__ ghist,
                                               const u32* __restrict__ gtail,
                                               float* __restrict__ out) {
  __shared__ u64 keys[1024];
  __shared__ u32 wsum[4], selB[4];
  __shared__ u32 s_cnt;
  const int tid = threadIdx.x;
  const int lane = tid & 63;
  const u64 lmask = (1ull << lane) - 1ull;
  const int b = blockIdx.x;
  const float4* ks4 = (const float4*)(keptScore + (size_t)b * NTOT);

  if (tid == 0) s_cnt = 0u;
  suffix_fast<NHB>(ghist + (size_t)b * NHB, (u32)MAXDET, wsum, selB);
  const u32 specTotal = selB[3];
  const u32 totalAll = specTotal + gtail[b];
  const u32 target = totalAll < (u32)MAXDET ? totalAll : (u32)MAXDET;
  const u32 F0 = selB[0];
  const u32 selSpec = selB[1];
  const bool fast = (totalAll != 0u) && (specTotal >= target) && (selSpec <= (u32)CAP);
  int SZ = CAP;

  if (totalAll != 0u) {
    if (fast) {
      for (int base = 0; base < NTOT / 4; base += 2048) {
        float4 v[8];
#pragma unroll
        for (int p = 0; p < 8; ++p) {
          int q = base + tid + (p << 8);
          if (q < NTOT / 4) v[p] = ks4[q];
        }
#pragma unroll
        for (int p = 0; p < 8; ++p) {
          int q = base + tid + (p << 8);
          if (q < NTOT / 4) {
            float vv[4] = {v[p].x, v[p].y, v[p].z, v[p].w};
#pragma unroll
            for (int e = 0; e < 4; ++e) {
              float s = vv[e];
              bool sel = false;
              u32 bits = 0;
              if (s > SPEC_THRF) {
                bits = __float_as_uint(s);
                u32 h = (bits >> 9) - HB0;
                if (h > NHB - 1) h = NHB - 1;
                sel = (h >= F0);
              }
              u64 ms = __ballot(sel);
              if (ms) {
                u32 bs;
                if (lane == 0) bs = atomicAdd(&s_cnt, (u32)__popcll(ms));
                bs = __shfl(bs, 0);
                if (sel)
                  keys[bs + (u32)__popcll(ms & lmask)] =
                      ((u64)bits << 32) | (~(u32)(q * 4 + e));
              }
            }
          }
        }
      }
      __syncthreads();
      for (int i = (int)selSpec + tid; i < CAP; i += 256) keys[i] = 0ull;
      __syncthreads();
      bitonic_sort(keys, CAP, tid);
      SZ = CAP;
    } else {
      // Exact fallback: serial 80-way merge of the sorted per-class lists.
      if (tid < 64) {
        const int c0 = lane, c1 = 64 + lane;
        const bool has1 = (c1 < NCLS);
        const float* ls0 = keptScore + ((size_t)b * NCLS + c0) * MAXDET;
        const float* ls1 = keptScore + ((size_t)b * NCLS + (has1 ? c1 : c0)) * MAXDET;
        int h0 = 0, h1 = 0;
        float v0 = ls0[0], w0v = ls0[1];
        float v1 = has1 ? ls1[0] : -INFINITY;
        float w1v = has1 ? ls1[1] : -INFINITY;
        for (int r = 0; r < (int)target; ++r) {
          float bs; int bcl;
          if (has1 && v1 > v0) { bs = v1; bcl = c1; } else { bs = v0; bcl = c0; }
#pragma unroll
          for (int off = 32; off > 0; off >>= 1) {
            float os = __shfl_xor(bs, off);
            int oc = __shfl_xor(bcl, off);
            if (os > bs || (os == bs && oc < bcl)) { bs = os; bcl = oc; }
          }
          if (bcl == c0) {
            keys[1023 - r] = ((u64)__float_as_uint(bs) << 32) | (~(u32)(c0 * MAXDET + h0));
            ++h0; v0 = w0v; w0v = (h0 + 1 < MAXDET) ? ls0[h0 + 1] : -INFINITY;
          } else if (has1 && bcl == c1) {
            keys[1023 - r] = ((u64)__float_as_uint(bs) << 32) | (~(u32)(c1 * MAXDET + h1));
            ++h1; v1 = w1v; w1v = (h1 + 1 < MAXDET) ? ls1[h1 + 1] : -INFINITY;
          }
        }
      }
      __syncthreads();
      SZ = 1024;
    }
  }

  for (int r = tid; r < MAXDET; r += 256) {
    const bool valid = (u32)r < target;
    float s = -1.0f, pm = -1.0f, pl = -1.0f, cl = -1.0f;
    float4 ob; ob.x = ob.y = ob.z = ob.w = -1.0f;
    if (valid) {
      u64 key = keys[SZ - 1 - r];
      u32 fp = ~((u32)key);
      int c = (int)(fp / MAXDET);
      int slot = (int)(fp - (u32)c * MAXDET);
      int n = keptN[((size_t)b * NCLS + c) * MAXDET + slot];
      s = __uint_as_float((u32)(key >> 32));
      cl = (float)c;
      size_t nb = (size_t)b * NBOX + (u32)n;
      ob = ((const float4*)boxes)[nb];
      const float* rp = rel + nb * NREL;
      float vr[NREL];
#pragma unroll
      for (int p = 0; p < NREL; ++p) vr[p] = rp[p];  // all loads in flight
      float best = vr[0]; int bi = 0;
#pragma unroll
      for (int p = 1; p < NREL; ++p) { if (vr[p] > best) { best = vr[p]; bi = p; } }
      pm = best; pl = (float)bi;
    }
    ((float4*)out)[(size_t)b * MAXDET + r] = ob;
    const int sbase = NBATCH * MAXDET * 4;
    out[sbase + b * MAXDET + r] = s;
    out[sbase + NBATCH * MAXDET + b * MAXDET + r] = cl;
    out[sbase + 2 * NBATCH * MAXDET + b * MAXDET + r] = pm;
    out[sbase + 3 * NBATCH * MAXDET + b * MAXDET + r] = pl;
  }
}

extern "C" void kernel_launch(void* const* d_in, const int* in_sizes, int n_in,
                              void* d_out, int out_size, void* d_ws, size_t ws_size,
                              hipStream_t stream) {
  (void)in_sizes; (void)n_in; (void)out_size;
  const float* boxes = (const float*)d_in[0];
  const float* cls   = (const float*)d_in[1];
  const float* rel   = (const float*)d_in[2];
  float* out = (float*)d_out;
  char* ws = (char*)d_ws;

  const size_t trBytes = (size_t)NBATCH * NCLS * NBOX * 4;  // 51.2 MB
  const size_t NP = NBATCH * NCLS;                          // 640 problems

  float* colS = (float*)ws;
  size_t off = 0;
  const size_t oKeptScore = off; off += NP * MAXDET * 4;
  const size_t oKeptN     = off; off += NP * MAXDET * 4;
  const size_t oKeptCount = off; off += NP * 4;
  const size_t oFlags     = off; off += NP * 4;
  const size_t oSelCnt    = off; off += NP * 4;
  const size_t oTotCnt    = off; off += NP * 4;
  const size_t oKeysSep   = off; off += NP * CAP * 8;
  const size_t oGhist     = off; off += (size_t)NBATCH * NHB * 4;
  const size_t oGtail     = off; off += NBATCH * 4;
  const size_t kbaseBytes = off;

  const bool useTr = ws_size >= trBytes + kbaseBytes;
  char* kbase = useTr ? (ws + trBytes) : ws;

  float* keptScore = (float*)(kbase + oKeptScore);
  int* keptN = (int*)(kbase + oKeptN);
  int* keptCount = (int*)(kbase + oKeptCount);
  int* flags = (int*)(kbase + oFlags);
  int* selCnt = (int*)(kbase + oSelCnt);
  int* totCnt = (int*)(kbase + oTotCnt);
  u64* keysSep = (u64*)(kbase + oKeysSep);
  u32* ghist = (u32*)(kbase + oGhist);
  u32* gtail = (u32*)(kbase + oGtail);

  u64* keysBase = useTr ? (u64*)colS : keysSep;
  const size_t kstride = useTr ? (size_t)(NBOX / 2) : (size_t)CAP;

  if (useTr) {
    k_tr<<<dim3((NBOX + 63) / 64, NBATCH), 256, 0, stream>>>(cls, colS, ghist, gtail);
    k_sel<1><<<NP, 256, 0, stream>>>(colS, keysBase, kstride, selCnt, totCnt, flags);
  } else {
    k_zero<<<NBATCH, 256, 0, stream>>>(ghist, gtail);
    k_sel<NCLS><<<NP, 256, 0, stream>>>(cls, keysBase, kstride, selCnt, totCnt, flags);
  }
  k_walk<<<NP, 512, 0, stream>>>(boxes, keysBase, kstride, selCnt, totCnt,
                                 keptScore, keptN, keptCount, flags, ghist, gtail);
  k_slow<<<NP, 256, 0, stream>>>(boxes, cls, keptScore, keptN, keptCount, flags,
                                 ghist, gtail);
  k_osort<<<NBATCH, 256, 0, stream>>>(boxes, rel, keptScore, keptN, ghist, gtail, out);
}

// Round 13
// 140.289 us; speedup vs baseline: 1.3638x; 1.2028x over previous
//
#include <hip/hip_runtime.h>
#include <hip/hip_bf16.h>
#include <math.h>

#define NBATCH 8
#define NBOX   20000
#define NCLS   80
#define NREL   51
#define MAXDET 300
#define NTOT   (NCLS * MAXDET)      // 24000
#define CAP    512
#define SPECCAP 2560
#define NHB    3328
#define HB0    (0x3F666666u >> 9)   // bucket base = bits(0.9f) >> 9
#define TARGETK 480u
#define SCORE_THR 0.05f
#define SPEC_THRF 0.9f
#define WWAVES 8

typedef unsigned long long u64;
typedef unsigned int u32;

// IoU > 0.5, explicit IEEE div (slow path only).
__device__ __forceinline__ bool iou_sup(float ax1, float ay1, float ax2, float ay2, float aarea,
                                        float bx1, float by1, float bx2, float by2, float barea) {
  float ix1 = fmaxf(ax1, bx1);
  float iy1 = fmaxf(ay1, by1);
  float ix2 = fminf(ax2, bx2);
  float iy2 = fminf(ay2, by2);
  float dw = fmaxf(__fsub_rn(ix2, ix1), 0.0f);
  float dh = fmaxf(__fsub_rn(iy2, iy1), 0.0f);
  float inter = __fmul_rn(dw, dh);
  float uni = __fsub_rn(__fadd_rn(aarea, barea), inter);
  if (!(uni > 0.0f)) return false;
  return __fdiv_rn(inter, uni) > 0.5f;
}

__device__ __forceinline__ bool iou_gt_half(float ax1, float ay1, float ax2, float ay2,
                                            float bx1, float by1, float bx2, float by2) {
  float aa = __fmul_rn(__fsub_rn(ax2, ax1), __fsub_rn(ay2, ay1));
  float ab = __fmul_rn(__fsub_rn(bx2, bx1), __fsub_rn(by2, by1));
  return iou_sup(ax1, ay1, ax2, ay2, aa, bx1, by1, bx2, by2, ab);
}

// Bit-exact div-free IoU>0.5 in PURE f32:
//   rn32(inter/uni) > 0.5  ⟺  inter/uni > 0.5(1+2^-24)   (tie->even = 0.5)
//   f32 test inter > 0.5*uni differs only if a float inter lies in
//   (0.5uni, 0.5uni(1+2^-24)] — impossible: succ(a) = a(1+2^-23/m), m<2.
__device__ __forceinline__ bool iou_sup_fast(float ax1, float ay1, float ax2, float ay2,
                                             float aarea, float bx1, float by1, float bx2,
                                             float by2, float barea) {
  float ix1 = fmaxf(ax1, bx1);
  float iy1 = fmaxf(ay1, by1);
  float ix2 = fminf(ax2, bx2);
  float iy2 = fminf(ay2, by2);
  float dw = fmaxf(__fsub_rn(ix2, ix1), 0.0f);
  float dh = fmaxf(__fsub_rn(iy2, iy1), 0.0f);
  float inter = __fmul_rn(dw, dh);
  float uni = __fsub_rn(__fadd_rn(aarea, barea), inter);
  return (uni > 0.0f) && (inter > __fmul_rn(0.5f, uni));
}

#define CEXR(x, y, asc) { bool sw_ = (asc) ? ((x) > (y)) : ((x) < (y)); \
                          if (sw_) { u64 t_ = (x); (x) = (y); (y) = t_; } }

// Bitonic sort ascending over SZ u64 keys in LDS; 256-thread block.
__device__ __forceinline__ void bitonic_sort(u64* keys, int SZ, int tid) {
  for (int k = 2; k <= SZ; k <<= 1) {
    for (int j = k >> 1; j >= 4; j >>= 1) {
      for (int v = tid; v < (SZ >> 1); v += 256) {
        int i = ((v & ~(j - 1)) << 1) | (v & (j - 1));
        int p = i | j;
        bool asc = ((i & k) == 0);
        u64 a = keys[i], b = keys[p];
        bool sw = asc ? (a > b) : (a < b);
        if (sw) { keys[i] = b; keys[p] = a; }
      }
      __syncthreads();
    }
    if (tid < (SZ >> 2)) {
      ulonglong2* k2 = (ulonglong2*)keys;
      ulonglong2 lo = k2[tid * 2], hi = k2[tid * 2 + 1];
      u64 a = lo.x, b = lo.y, c = hi.x, d = hi.y;
      int i0 = tid << 2;
      if (k == 2) {
        CEXR(a, b, true); CEXR(c, d, false);
      } else {
        bool asc = ((i0 & k) == 0);
        CEXR(a, c, asc); CEXR(b, d, asc);  // j = 2
        CEXR(a, b, asc); CEXR(c, d, asc);  // j = 1
      }
      lo.x = a; lo.y = b; hi.x = c; hi.y = d;
      k2[tid * 2] = lo; k2[tid * 2 + 1] = hi;
    }
    __syncthreads();
  }
}

// Barrier-light suffix select over NB buckets (LDS or global hist):
// minimal suffix >= min(total, cap). sout: [0]=bucket [1]=sel [2]=above [3]=total.
template <int NB>
__device__ __forceinline__ void suffix_fast(const u32* hist, u32 cap, u32* wsum4, u32* sout) {
  const int tid = threadIdx.x, lane = tid & 63, w = tid >> 6;
  const int G = NB / 256;
  u32 v = 0;
  const int hb = tid * G;
#pragma unroll
  for (int t = 0; t < G; ++t) v += hist[hb + t];
  u32 s = v;
#pragma unroll
  for (int off = 1; off < 64; off <<= 1) {
    u32 t2 = __shfl_down(s, off);
    if (lane + off < 64) s += t2;
  }
  if (lane == 0) wsum4[w] = s;
  __syncthreads();
  u32 total = wsum4[0] + wsum4[1] + wsum4[2] + wsum4[3];
  u32 after = 0;
#pragma unroll
  for (int ww = 1; ww < 4; ++ww) if (ww > w) after += wsum4[ww];
  u32 inc = s + after;
  u32 exc = inc - v;
  if (tid == 0) {
    sout[3] = total;
    if (total == 0u) { sout[0] = 0u; sout[1] = 0u; sout[2] = 0u; }
  }
  u32 target = total < cap ? total : cap;
  if (total != 0u && inc >= target && exc < target) {  // exactly one thread
    u32 acc = exc;
    for (int u = hb + G - 1; u >= hb; --u) {
      acc += hist[u];
      if (acc >= target) { sout[0] = (u32)u; sout[1] = acc; sout[2] = acc - hist[u]; break; }
    }
  }
  __syncthreads();
}

// Transpose cls (B,N,C) -> colS (B,C,N). Block x==0 zeroes per-batch topk scratch.
__global__ __launch_bounds__(256) void k_tr(const float* __restrict__ cls,
                                            float* __restrict__ colS,
                                            u32* __restrict__ ghist,
                                            u32* __restrict__ gtail) {
  __shared__ float tile[NCLS * 65];
  const int tid = threadIdx.x;
  const int b = blockIdx.y;
  const int n0 = blockIdx.x * 64;
  if (blockIdx.x == 0) {
    for (int i = tid; i < NHB; i += 256) ghist[b * NHB + i] = 0u;
    if (tid == 0) gtail[b] = 0u;
  }
  const int rows = (NBOX - n0) < 64 ? (NBOX - n0) : 64;
  const float4* src4 = (const float4*)(cls + ((size_t)b * NBOX + n0) * NCLS);
  const int nq = rows * (NCLS / 4);
  for (int i = tid; i < nq; i += 256) {
    int rr = i / (NCLS / 4);
    int c4 = i - rr * (NCLS / 4);
    float4 v = src4[i];
    tile[(c4 * 4 + 0) * 65 + rr] = v.x;
    tile[(c4 * 4 + 1) * 65 + rr] = v.y;
    tile[(c4 * 4 + 2) * 65 + rr] = v.z;
    tile[(c4 * 4 + 3) * 65 + rr] = v.w;
  }
  __syncthreads();
  float4* dst4 = (float4*)colS;
  for (int i = tid; i < NCLS * 16; i += 256) {
    int c = i >> 4, nl = i & 15;
    if (nl * 4 < rows) {
      float4 v;
      v.x = tile[c * 65 + nl * 4 + 0];
      v.y = tile[c * 65 + nl * 4 + 1];
      v.z = tile[c * 65 + nl * 4 + 2];
      v.w = tile[c * 65 + nl * 4 + 3];
      dst4[(((size_t)b * NCLS + c) * NBOX + n0) / 4 + nl] = v;
    }
  }
}

// Zero scratch when transpose path is unavailable.
__global__ __launch_bounds__(256) void k_zero(u32* __restrict__ ghist,
                                              u32* __restrict__ gtail) {
  const int b = blockIdx.x;
  const int tid = threadIdx.x;
  for (int i = tid; i < NHB; i += 256) ghist[b * NHB + i] = 0u;
  if (tid == 0) gtail[b] = 0u;
}

template <int STRIDE>
__device__ __forceinline__ float4 load4s(const float* col, int q) {
  if (STRIDE == 1) return ((const float4*)col)[q];
  float4 v;
  v.x = col[(size_t)(q * 4 + 0) * STRIDE];
  v.y = col[(size_t)(q * 4 + 1) * STRIDE];
  v.z = col[(size_t)(q * 4 + 2) * STRIDE];
  v.w = col[(size_t)(q * 4 + 3) * STRIDE];
  return v;
}

// Phase A: single scan + speculative (>0.9) side buffer + flat 512-ULP histogram ->
// exact top-~TARGETK selection -> bitonic sort -> sorted keys to global.
template <int STRIDE>
__global__ __launch_bounds__(256) void k_sel(const float* __restrict__ scores,
                                             u64* __restrict__ keysBase, size_t kstride,
                                             int* __restrict__ selCnt,
                                             int* __restrict__ totCnt,
                                             int* __restrict__ flags) {
  __shared__ __align__(16) char smem[SPECCAP * 8 + NHB * 4 + CAP * 8];
  u64* side = (u64*)smem;
  u32* hist = (u32*)(smem + SPECCAP * 8);
  u64* keys = (u64*)(smem + SPECCAP * 8 + NHB * 4);
  __shared__ u32 wsum[4], selB[4], twave[4];
  __shared__ u32 s_scnt, s_cnt;

  const int tid = threadIdx.x;
  const int lane = tid & 63;
  const int w = tid >> 6;
  const u64 lmask = (1ull << lane) - 1ull;
  const int bc = blockIdx.x;
  const int b = bc / NCLS, c = bc % NCLS;
  const float* col = (STRIDE == 1) ? (scores + (size_t)bc * NBOX)
                                   : (scores + (size_t)b * NBOX * NCLS + c);

  for (int i = tid; i < NHB; i += 256) hist[i] = 0u;
  if (tid == 0) { s_scnt = 0u; s_cnt = 0u; }
  __syncthreads();

  u32 tailc = 0;
  for (int base = 0; base < NBOX / 4; base += 2048) {
    float4 v[8];
#pragma unroll
    for (int p = 0; p < 8; ++p) {
      int q = base + tid + (p << 8);
      if (q < NBOX / 4) v[p] = load4s<STRIDE>(col, q);
    }
#pragma unroll
    for (int p = 0; p < 8; ++p) {
      int q = base + tid + (p << 8);
      if (q < NBOX / 4) {
        float vv[4] = {v[p].x, v[p].y, v[p].z, v[p].w};
#pragma unroll
        for (int e = 0; e < 4; ++e) {
          float s = vv[e];
          bool spec = s > SPEC_THRF;
          if (s > SCORE_THR && !spec) ++tailc;
          u64 mb = __ballot(spec);
          if (mb) {
            u32 bs;
            if (lane == 0) bs = atomicAdd(&s_scnt, (u32)__popcll(mb));
            bs = __shfl(bs, 0);
            if (spec) {
              u32 bits = __float_as_uint(s);
              u32 pos = bs + (u32)__popcll(mb & lmask);
              if (pos < SPECCAP) side[pos] = ((u64)bits << 32) | (~(u32)(q * 4 + e));
              u32 h = (bits >> 9) - HB0;
              if (h > NHB - 1) h = NHB - 1;
              atomicAdd(&hist[h], 1u);
            }
          }
        }
      }
    }
  }
  u32 tr = tailc;
#pragma unroll
  for (int off = 1; off < 64; off <<= 1) tr += __shfl_down(tr, off);
  if (lane == 0) twave[w] = tr;
  __syncthreads();

  const u32 specCount = s_scnt;
  const u32 tailSum = twave[0] + twave[1] + twave[2] + twave[3];
  const u32 totalAll = specCount + tailSum;

  if (totalAll == 0u) {
    if (tid == 0) { selCnt[bc] = 0; totCnt[bc] = 0; flags[bc] = 0; }
    return;
  }
  const u32 target = totalAll < TARGETK ? totalAll : TARGETK;
  if (specCount < target || specCount > SPECCAP) {
    if (tid == 0) { selCnt[bc] = 0; totCnt[bc] = (int)totalAll; flags[bc] = 1; }
    return;
  }

  suffix_fast<NHB>(hist, target, wsum, selB);
  const u32 F0 = selB[0];
  const u32 selCount = selB[1];
  if (selCount > CAP) {
    if (tid == 0) { selCnt[bc] = 0; totCnt[bc] = (int)totalAll; flags[bc] = 1; }
    return;
  }

  const int iters = (int)((specCount + 255u) >> 8);
  for (int it2 = 0; it2 < iters; ++it2) {
    u32 idx = (u32)it2 * 256u + (u32)tid;
    bool act = idx < specCount;
    u64 key = act ? side[idx] : 0ull;
    u32 bits = (u32)(key >> 32);
    u32 h = (bits >> 9) - HB0;
    if (h > NHB - 1) h = NHB - 1;
    bool sel = act && (h >= F0);
    u64 ms = __ballot(sel);
    if (ms) {
      u32 bs;
      if (lane == 0) bs = atomicAdd(&s_cnt, (u32)__popcll(ms));
      bs = __shfl(bs, 0);
      if (sel) keys[bs + (u32)__popcll(ms & lmask)] = key;
    }
  }
  __syncthreads();
  for (int i = (int)selCount + tid; i < CAP; i += 256) keys[i] = 0ull;
  __syncthreads();

  bitonic_sort(keys, CAP, tid);

  u64* kout = keysBase + (size_t)bc * kstride;
  for (int i = tid; i < CAP; i += 256) kout[i] = keys[i];
  if (tid == 0) { selCnt[bc] = (int)selCount; totCnt[bc] = (int)totalAll; flags[bc] = 0; }
}

// Exact reference-style greedy NMS (slow path), 512-thread version, called inline
// from k_walk for flagged/exhausted problems. Reads original strided cls.
// Writes keptScore/keptN/keptCount and contributes to the per-batch histogram.
__device__ void slow_path(const float* __restrict__ boxes,
                          const float* __restrict__ cls, int bc,
                          float* __restrict__ keptScore, int* __restrict__ keptN,
                          int* __restrict__ keptCount,
                          u32* __restrict__ ghist, u32* __restrict__ gtail,
                          char* smem) {
  u32* sup = (u32*)smem;                       // [(NBOX+31)/32] = 625 u32 @0
  u64* red = (u64*)(smem + 2560);              // [512] u64 @2560 (8B aligned)
  float4* sbx = (float4*)(smem + 6656);        // 16B (6656 % 16 == 0)
  int* s_kept = (int*)(smem + 6672);
  const int tid = threadIdx.x;
  const int b = bc / NCLS, c = bc % NCLS;
  const float* col = cls + (size_t)b * NBOX * NCLS + c;

  for (int i = tid; i < (NBOX + 31) / 32; i += 512) sup[i] = 0u;
  if (tid == 0) *s_kept = 0;
  __syncthreads();
  for (int it = 0; it < MAXDET; ++it) {
    u64 best = 0ull;
    for (int n = tid; n < NBOX; n += 512) {
      if ((sup[n >> 5] >> (n & 31)) & 1u) continue;
      float s = col[(size_t)n * NCLS];
      if (s > SCORE_THR) {
        u64 key = ((u64)__float_as_uint(s) << 32) | (~(u32)n);
        if (key > best) best = key;
      }
    }
    red[tid] = best;
    __syncthreads();
    for (int off = 256; off > 0; off >>= 1) {
      if (tid < off) { u64 o = red[tid + off]; if (o > red[tid]) red[tid] = o; }
      __syncthreads();
    }
    u64 win = red[0];
    if (win == 0ull) break;
    u32 nw = ~((u32)win);
    if (tid == 0) {
      int k = *s_kept;
      keptScore[bc * MAXDET + k] = __uint_as_float((u32)(win >> 32));
      keptN[bc * MAXDET + k] = (int)nw;
      *s_kept = k + 1;
      *sbx = ((const float4*)boxes)[(size_t)b * NBOX + nw];
    }
    __syncthreads();
    float4 bx = *sbx;
    for (int n = tid; n < NBOX; n += 512) {
      float4 cb = ((const float4*)boxes)[(size_t)b * NBOX + n];
      if (iou_gt_half(bx.x, bx.y, bx.z, bx.w, cb.x, cb.y, cb.z, cb.w))
        atomicOr(&sup[n >> 5], 1u << (n & 31));
    }
    if (tid == 0) atomicOr(&sup[nw >> 5], 1u << (nw & 31));
    __syncthreads();
  }
  __syncthreads();
  const int kept = *s_kept;
  for (int r = kept + tid; r < MAXDET; r += 512) {
    keptScore[bc * MAXDET + r] = -INFINITY;
    keptN[bc * MAXDET + r] = 0;
  }
  for (int rr = tid; rr < kept; rr += 512) {
    float s = keptScore[bc * MAXDET + rr];
    if (s > SPEC_THRF) {
      u32 h = (__float_as_uint(s) >> 9) - HB0;
      if (h > NHB - 1) h = NHB - 1;
      atomicAdd(&ghist[b * NHB + h], 1u);
    } else {
      atomicAdd(&gtail[b], 1u);
    }
  }
  if (tid == 0) keptCount[bc] = kept;
}

// Phase B: gather candidate boxes + tile-parallel greedy NMS walk (8 waves, f32-exact
// IoU) — the round-9 structure. Flagged/exhausted problems run the exact slow path
// inline (no separate dispatch). On success, histograms kept scores for the top-k.
__global__ __launch_bounds__(512) void k_walk(const float* __restrict__ boxes,
                                              const float* __restrict__ cls,
                                              const u64* __restrict__ keysBase, size_t kstride,
                                              const int* __restrict__ selCnt,
                                              const int* __restrict__ totCnt,
                                              float* __restrict__ keptScore,
                                              int* __restrict__ keptN,
                                              int* __restrict__ keptCount,
                                              const int* __restrict__ flags,
                                              u32* __restrict__ ghist,
                                              u32* __restrict__ gtail) {
  // Fast layout: keys u64[512]@0; candbox f4[512]@4096; carea f32[512]@12288;
  // keptbox f4[300]@14336; karea@19136; kn@20336; ksc@21536; ends 22736.
  // Slow layout (aliased): sup u32[625]@0; red u64[512]@2560; sbx@6656; s_kept@6672.
  __shared__ __align__(16) char smem[22784];
  u64* keys = (u64*)smem;
  float4* candbox = (float4*)(smem + 4096);
  float* carea = (float*)(smem + 12288);
  float4* keptbox = (float4*)(smem + 14336);
  float* karea = (float*)(smem + 19136);
  int* kn = (int*)(smem + 20336);
  float* ksc = (float*)(smem + 21536);
  __shared__ u64 supW[WWAVES];
  __shared__ u64 mpart[WWAVES][64];
  __shared__ int s_kept;

  const int tid = threadIdx.x;
  const int lane = tid & 63;
  const int w = tid >> 6;
  const u64 lmask = (1ull << lane) - 1ull;
  const int bc = blockIdx.x;
  const int b = bc / NCLS;

  if (flags[bc] != 0) {  // speculation failed in k_sel: exact slow path inline
    slow_path(boxes, cls, bc, keptScore, keptN, keptCount, ghist, gtail, smem);
    return;
  }
  const u32 selCount = (u32)selCnt[bc];
  const u32 totalAll = (u32)totCnt[bc];

  const u64* kin = keysBase + (size_t)bc * kstride;
  for (int i = tid; i < CAP; i += 512) keys[i] = kin[i];
  if (tid == 0) s_kept = 0;
  __syncthreads();

  for (int i = tid; i < (int)selCount; i += 512) {
    int pos = CAP - 1 - i;
    u32 n = ~((u32)keys[pos]);
    float4 bb = ((const float4*)boxes)[(size_t)b * NBOX + n];
    candbox[pos] = bb;
    carea[pos] = __fmul_rn(__fsub_rn(bb.z, bb.x), __fsub_rn(bb.w, bb.y));
  }
  __syncthreads();

  const u32 ntile = (selCount + 63u) >> 6;
  for (u32 t = 0; t < ntile; ++t) {
    const int kept0 = s_kept;
    if (kept0 >= MAXDET) break;
    const u32 r = t * 64u + (u32)lane;
    const bool valid = r < selCount;
    const int si = valid ? (CAP - 1 - (int)r) : (CAP - 1);
    float4 mybox = candbox[si];
    float marea = carea[si];
    bool sup = false;
    for (int k = w; k < kept0; k += WWAVES) {
      float4 kb = keptbox[k];
      if (iou_sup_fast(kb.x, kb.y, kb.z, kb.w, karea[k],
                       mybox.x, mybox.y, mybox.z, mybox.w, marea))
        sup = true;
    }
    u64 bal = __ballot(sup);
    if (lane == 0) supW[w] = bal;
    u64 mw = 0ull;
    const int ebase = w * 8;
#pragma unroll
    for (int ee = 0; ee < 8; ++ee) {
      const int e = ebase + ee;
      int ei = CAP - 1 - (int)(t * 64u) - e;
      float4 eb = candbox[ei];
      if (e < lane && iou_sup_fast(eb.x, eb.y, eb.z, eb.w, carea[ei],
                                   mybox.x, mybox.y, mybox.z, mybox.w, marea))
        mw |= 1ull << e;
    }
    mpart[w][lane] = mw;
    __syncthreads();
    if (w == 0) {
      u64 prior = 0ull, m = 0ull;
#pragma unroll
      for (int ww = 0; ww < WWAVES; ++ww) {
        prior |= supW[ww];
        m |= mpart[ww][lane];
      }
      u64 remaining = __ballot(valid) & ~prior;
      u64 keptmask = 0ull;
      const int room = MAXDET - kept0;
      while (remaining != 0ull && (int)__popcll(keptmask) < room) {
        int j = __ffsll((long long)remaining) - 1;
        keptmask |= 1ull << j;
        remaining &= ~(1ull << j);
        u64 supj = __ballot(((m >> j) & 1ull) != 0ull);
        remaining &= ~supj;
      }
      if ((keptmask >> lane) & 1ull) {
        int pos = kept0 + (int)__popcll(keptmask & lmask);
        u64 mykey = keys[CAP - 1 - (int)r];
        keptbox[pos] = mybox;
        karea[pos] = marea;
        kn[pos] = (int)(~((u32)mykey));
        ksc[pos] = __uint_as_float((u32)(mykey >> 32));
      }
      if (lane == 0) s_kept = kept0 + (int)__popcll(keptmask);
    }
    __syncthreads();
  }

  const int kept = s_kept;
  const bool exhausted = (kept < MAXDET && selCount < totalAll);
  if (exhausted) {  // prefix exhausted: redo exactly, inline
    __syncthreads();
    slow_path(boxes, cls, bc, keptScore, keptN, keptCount, ghist, gtail, smem);
    return;
  }
  for (int rr = tid; rr < MAXDET; rr += 512) {
    keptScore[bc * MAXDET + rr] = (rr < kept) ? ksc[rr] : -INFINITY;
    keptN[bc * MAXDET + rr] = (rr < kept) ? kn[rr] : 0;
  }
  if (tid == 0) keptCount[bc] = kept;
  for (int rr = tid; rr < kept; rr += 512) {  // top-k histogram contribution
    float s = ksc[rr];
    if (s > SPEC_THRF) {
      u32 h = (__float_as_uint(s) >> 9) - HB0;
      if (h > NHB - 1) h = NHB - 1;
      atomicAdd(&ghist[b * NHB + h], 1u);
    } else {
      atomicAdd(&gtail[b], 1u);
    }
  }
}

// Top-k + outputs: suffix-select from prebuilt per-batch hist -> compact scan ->
// bitonic-512 (exact lax.top_k ties) -> emit. Fallback: exact serial 80-way merge.
__global__ __launch_bounds__(256) void k_osort(const float* __restrict__ boxes,
                                               const float* __restrict__ rel,
                                               const float* __restrict__ keptScore,
                                               const int* __restrict__ keptN,
                                               const u32* __restrict__ ghist,
                                               const u32* __restrict__ gtail,
                                               float* __restrict__ out) {
  __shared__ u64 keys[1024];
  __shared__ u32 wsum[4], selB[4];
  __shared__ u32 s_cnt;
  const int tid = threadIdx.x;
  const int lane = tid & 63;
  const u64 lmask = (1ull << lane) - 1ull;
  const int b = blockIdx.x;
  const float4* ks4 = (const float4*)(keptScore + (size_t)b * NTOT);

  if (tid == 0) s_cnt = 0u;
  suffix_fast<NHB>(ghist + (size_t)b * NHB, (u32)MAXDET, wsum, selB);
  const u32 specTotal = selB[3];
  const u32 totalAll = specTotal + gtail[b];
  const u32 target = totalAll < (u32)MAXDET ? totalAll : (u32)MAXDET;
  const u32 F0 = selB[0];
  const u32 selSpec = selB[1];
  const bool fast = (totalAll != 0u) && (specTotal >= target) && (selSpec <= (u32)CAP);
  int SZ = CAP;

  if (totalAll != 0u) {
    if (fast) {
      for (int base = 0; base < NTOT / 4; base += 2048) {
        float4 v[8];
#pragma unroll
        for (int p = 0; p < 8; ++p) {
          int q = base + tid + (p << 8);
          if (q < NTOT / 4) v[p] = ks4[q];
        }
#pragma unroll
        for (int p = 0; p < 8; ++p) {
          int q = base + tid + (p << 8);
          if (q < NTOT / 4) {
            float vv[4] = {v[p].x, v[p].y, v[p].z, v[p].w};
#pragma unroll
            for (int e = 0; e < 4; ++e) {
              float s = vv[e];
              bool sel = false;
              u32 bits = 0;
              if (s > SPEC_THRF) {
                bits = __float_as_uint(s);
                u32 h = (bits >> 9) - HB0;
                if (h > NHB - 1) h = NHB - 1;
                sel = (h >= F0);
              }
              u64 ms = __ballot(sel);
              if (ms) {
                u32 bs;
                if (lane == 0) bs = atomicAdd(&s_cnt, (u32)__popcll(ms));
                bs = __shfl(bs, 0);
                if (sel)
                  keys[bs + (u32)__popcll(ms & lmask)] =
                      ((u64)bits << 32) | (~(u32)(q * 4 + e));
              }
            }
          }
        }
      }
      __syncthreads();
      for (int i = (int)selSpec + tid; i < CAP; i += 256) keys[i] = 0ull;
      __syncthreads();
      bitonic_sort(keys, CAP, tid);
      SZ = CAP;
    } else {
      // Exact fallback: serial 80-way merge of the sorted per-class lists.
      if (tid < 64) {
        const int c0 = lane, c1 = 64 + lane;
        const bool has1 = (c1 < NCLS);
        const float* ls0 = keptScore + ((size_t)b * NCLS + c0) * MAXDET;
        const float* ls1 = keptScore + ((size_t)b * NCLS + (has1 ? c1 : c0)) * MAXDET;
        int h0 = 0, h1 = 0;
        float v0 = ls0[0], w0v = ls0[1];
        float v1 = has1 ? ls1[0] : -INFINITY;
        float w1v = has1 ? ls1[1] : -INFINITY;
        for (int r = 0; r < (int)target; ++r) {
          float bs; int bcl;
          if (has1 && v1 > v0) { bs = v1; bcl = c1; } else { bs = v0; bcl = c0; }
#pragma unroll
          for (int off = 32; off > 0; off >>= 1) {
            float os = __shfl_xor(bs, off);
            int oc = __shfl_xor(bcl, off);
            if (os > bs || (os == bs && oc < bcl)) { bs = os; bcl = oc; }
          }
          if (bcl == c0) {
            keys[1023 - r] = ((u64)__float_as_uint(bs) << 32) | (~(u32)(c0 * MAXDET + h0));
            ++h0; v0 = w0v; w0v = (h0 + 1 < MAXDET) ? ls0[h0 + 1] : -INFINITY;
          } else if (has1 && bcl == c1) {
            keys[1023 - r] = ((u64)__float_as_uint(bs) << 32) | (~(u32)(c1 * MAXDET + h1));
            ++h1; v1 = w1v; w1v = (h1 + 1 < MAXDET) ? ls1[h1 + 1] : -INFINITY;
          }
        }
      }
      __syncthreads();
      SZ = 1024;
    }
  }

  for (int r = tid; r < MAXDET; r += 256) {
    const bool valid = (u32)r < target;
    float s = -1.0f, pm = -1.0f, pl = -1.0f, cl = -1.0f;
    float4 ob; ob.x = ob.y = ob.z = ob.w = -1.0f;
    if (valid) {
      u64 key = keys[SZ - 1 - r];
      u32 fp = ~((u32)key);
      int c = (int)(fp / MAXDET);
      int slot = (int)(fp - (u32)c * MAXDET);
      int n = keptN[((size_t)b * NCLS + c) * MAXDET + slot];
      s = __uint_as_float((u32)(key >> 32));
      cl = (float)c;
      size_t nb = (size_t)b * NBOX + (u32)n;
      ob = ((const float4*)boxes)[nb];
      const float* rp = rel + nb * NREL;
      float vr[NREL];
#pragma unroll
      for (int p = 0; p < NREL; ++p) vr[p] = rp[p];  // all loads in flight
      float best = vr[0]; int bi = 0;
#pragma unroll
      for (int p = 1; p < NREL; ++p) { if (vr[p] > best) { best = vr[p]; bi = p; } }
      pm = best; pl = (float)bi;
    }
    ((float4*)out)[(size_t)b * MAXDET + r] = ob;
    const int sbase = NBATCH * MAXDET * 4;
    out[sbase + b * MAXDET + r] = s;
    out[sbase + NBATCH * MAXDET + b * MAXDET + r] = cl;
    out[sbase + 2 * NBATCH * MAXDET + b * MAXDET + r] = pm;
    out[sbase + 3 * NBATCH * MAXDET + b * MAXDET + r] = pl;
  }
}

extern "C" void kernel_launch(void* const* d_in, const int* in_sizes, int n_in,
                              void* d_out, int out_size, void* d_ws, size_t ws_size,
                              hipStream_t stream) {
  (void)in_sizes; (void)n_in; (void)out_size;
  const float* boxes = (const float*)d_in[0];
  const float* cls   = (const float*)d_in[1];
  const float* rel   = (const float*)d_in[2];
  float* out = (float*)d_out;
  char* ws = (char*)d_ws;

  const size_t trBytes = (size_t)NBATCH * NCLS * NBOX * 4;  // 51.2 MB
  const size_t NP = NBATCH * NCLS;                          // 640 problems

  float* colS = (float*)ws;
  size_t off = 0;
  const size_t oKeptScore = off; off += NP * MAXDET * 4;
  const size_t oKeptN     = off; off += NP * MAXDET * 4;
  const size_t oKeptCount = off; off += NP * 4;
  const size_t oFlags     = off; off += NP * 4;
  const size_t oSelCnt    = off; off += NP * 4;
  const size_t oTotCnt    = off; off += NP * 4;
  const size_t oKeysSep   = off; off += NP * CAP * 8;
  const size_t oGhist     = off; off += (size_t)NBATCH * NHB * 4;
  const size_t oGtail     = off; off += NBATCH * 4;
  const size_t kbaseBytes = off;

  const bool useTr = ws_size >= trBytes + kbaseBytes;
  char* kbase = useTr ? (ws + trBytes) : ws;

  float* keptScore = (float*)(kbase + oKeptScore);
  int* keptN = (int*)(kbase + oKeptN);
  int* keptCount = (int*)(kbase + oKeptCount);
  int* flags = (int*)(kbase + oFlags);
  int* selCnt = (int*)(kbase + oSelCnt);
  int* totCnt = (int*)(kbase + oTotCnt);
  u64* keysSep = (u64*)(kbase + oKeysSep);
  u32* ghist = (u32*)(kbase + oGhist);
  u32* gtail = (u32*)(kbase + oGtail);

  u64* keysBase = useTr ? (u64*)colS : keysSep;
  const size_t kstride = useTr ? (size_t)(NBOX / 2) : (size_t)CAP;

  if (useTr) {
    k_tr<<<dim3((NBOX + 63) / 64, NBATCH), 256, 0, stream>>>(cls, colS, ghist, gtail);
    k_sel<1><<<NP, 256, 0, stream>>>(colS, keysBase, kstride, selCnt, totCnt, flags);
  } else {
    k_zero<<<NBATCH, 256, 0, stream>>>(ghist, gtail);
    k_sel<NCLS><<<NP, 256, 0, stream>>>(cls, keysBase, kstride, selCnt, totCnt, flags);
  }
  k_walk<<<NP, 512, 0, stream>>>(boxes, cls, keysBase, kstride, selCnt, totCnt,
                                 keptScore, keptN, keptCount, flags, ghist, gtail);
  k_osort<<<NBATCH, 256, 0, stream>>>(boxes, rel, keptScore, keptN, ghist, gtail, out);
}